// Round 9
// baseline (512.016 us; speedup 1.0000x reference)
//
#include <hip/hip_runtime.h>
#include <cmath>

typedef __attribute__((ext_vector_type(8))) short short8;
typedef __attribute__((ext_vector_type(4))) float floatx4;

// ---------- helpers ----------
__device__ __forceinline__ unsigned short rnbf(float f) {
    unsigned u = __float_as_uint(f);
    u += 0x7fffu + ((u >> 16) & 1u);
    return (unsigned short)(u >> 16);
}
__device__ __forceinline__ float bf2f(unsigned short h) {
    return __uint_as_float(((unsigned)h) << 16);
}
__device__ __forceinline__ int rfl(int v) { return __builtin_amdgcn_readfirstlane(v); }
__device__ __forceinline__ float eAct(unsigned ry, float we0, float we1, float bev) {
    float a0 = __uint_as_float(ry & 0xFFFF0000u);
    float a1 = __uint_as_float(ry << 16);
    return fmaxf(fmaf(a1, we1, fmaf(a0, we0, bev)), 0.f);
}
__device__ __forceinline__ unsigned vidx(int x, unsigned pl, int lane) {
    return (((unsigned)x >> 24) & 7u)*pl + (unsigned)(x & 0xFFFFFF)*64u + (unsigned)lane;
}
__device__ __forceinline__ void mstep(int r, float v, int& cur, float& mx, float& add) {
    bool nb = (r != cur);
    add += nb ? mx : 0.f;
    mx = nb ? v : fmaxf(mx, v);
    cur = r;
}
// 8-way relation-select accumulate (wave-uniform r)
__device__ __forceinline__ void acc8(int r, float v,
    float& a0, float& a1, float& a2, float& a3,
    float& a4, float& a5, float& a6, float& a7)
{
    a0 += (r==0)?v:0.f; a1 += (r==1)?v:0.f; a2 += (r==2)?v:0.f; a3 += (r==3)?v:0.f;
    a4 += (r==4)?v:0.f; a5 += (r==5)?v:0.f; a6 += (r==6)?v:0.f; a7 += (r==7)?v:0.f;
}

// ================= fallback sort pipeline (N > 2^17) =================
__global__ void k_histd(const int* __restrict__ ei, const int* __restrict__ et,
                        int* __restrict__ deg8, int E)
{
    int e = blockIdx.x*blockDim.x + threadIdx.x;
    if (e < E) atomicAdd(&deg8[ei[E + e]*8 + et[e]], 1);
}
#define SCHUNK 1024
__global__ void k_bsum(const int* __restrict__ deg, int* __restrict__ bsum, int K)
{
    __shared__ int s[256];
    int b = blockIdx.x, t = threadIdx.x;
    int base = b*SCHUNK;
    int v = 0;
    for (int k = t; k < SCHUNK; k += 256) { int i = base + k; v += (i < K) ? deg[i] : 0; }
    s[t] = v; __syncthreads();
    for (int o = 128; o; o >>= 1) { if (t < o) s[t] += s[t+o]; __syncthreads(); }
    if (t == 0) bsum[b] = s[0];
}
__global__ void k_bscan(int* __restrict__ bsum, int nb)
{
    __shared__ int ts[256];
    int t = threadIdx.x;
    int v[4]; int loc = 0;
    #pragma unroll
    for (int u = 0; u < 4; ++u) { int i = t*4+u; v[u] = (i < nb) ? bsum[i] : 0; loc += v[u]; }
    ts[t] = loc; __syncthreads();
    for (int o = 1; o < 256; o <<= 1) {
        int add = (t >= o) ? ts[t-o] : 0;
        __syncthreads();
        ts[t] += add;
        __syncthreads();
    }
    int excl = ts[t] - loc;
    #pragma unroll
    for (int u = 0; u < 4; ++u) {
        int i = t*4+u;
        if (i < nb) bsum[i] = excl;
        excl += v[u];
    }
}
__global__ void k_bapply(const int* __restrict__ deg, const int* __restrict__ bsum,
                         int* __restrict__ off, int* __restrict__ cursor, int K)
{
    __shared__ int ts[256];
    int b = blockIdx.x, t = threadIdx.x;
    int base = b*SCHUNK;
    int v[4]; int loc = 0;
    #pragma unroll
    for (int u = 0; u < 4; ++u) { int i = base + t*4 + u; v[u] = (i < K) ? deg[i] : 0; loc += v[u]; }
    ts[t] = loc; __syncthreads();
    for (int o = 1; o < 256; o <<= 1) {
        int add = (t >= o) ? ts[t-o] : 0;
        __syncthreads();
        ts[t] += add;
        __syncthreads();
    }
    int excl = ts[t] - loc + bsum[b];
    #pragma unroll
    for (int u = 0; u < 4; ++u) {
        int i = base + t*4 + u;
        if (i < K) { off[i] = excl; cursor[i] = excl; }
        excl += v[u];
        if (i == K-1) off[K] = excl;
    }
}
__global__ void k_scatd(const int* __restrict__ ei, const float* __restrict__ ea,
                        const int* __restrict__ et, int* __restrict__ cursor,
                        int2* __restrict__ srec, int E)
{
    int e = blockIdx.x*blockDim.x + threadIdx.x;
    if (e >= E) return;
    int rel = et[e];
    int key = ei[E + e]*8 + rel;
    int pos = atomicAdd(&cursor[key], 1);
    float2 a = ((const float2*)ea)[e];
    int xv = ei[e] | (rel << 24);
    int yv = ((int)rnbf(a.x) << 16) | (int)rnbf(a.y);
    srec[pos] = make_int2(xv, yv);
}

// ================= fast sort: bucket partition, self-contained =================
#define PB_KEYS 4096
#define PA_CH   4096
#define CNTB    512

__device__ __forceinline__ void dev_cnt(const int* __restrict__ ei,
                                        int* __restrict__ bktCnt,
                                        int E, int nbkt, int cb, int cgrid)
{
    __shared__ int cnt[512];
    for (int j = threadIdx.x; j < nbkt; j += 256) cnt[j] = 0;
    __syncthreads();
    int stride = cgrid*256;
    for (int e = cb*256 + threadIdx.x; e < E; e += stride)
        atomicAdd(&cnt[ei[E + e] >> 9], 1);
    __syncthreads();
    for (int j = threadIdx.x; j < nbkt; j += 256) {
        int c = cnt[j];
        if (c) atomicAdd(&bktCnt[j], c);
    }
}

// ---------- device body: encoder -> bf16 n-table + root1 (NO planes) ----------
__device__ __forceinline__ void dev_enc(
    const float* __restrict__ x,
    const float* __restrict__ Wn, const float* __restrict__ bn,
    const unsigned short* __restrict__ wpk, const float* __restrict__ b1,
    float* __restrict__ acc1, unsigned short* __restrict__ nb16,
    int N, int bid)
{
    int lane = threadIdx.x & 63;
    int wave = threadIdx.x >> 6;
    int n0 = bid*64 + 16*wave;
    int m = lane & 15, q = lane >> 4;
    // coalesced bf16 n-table write: lane = feature
    #pragma unroll 4
    for (int t = 0; t < 16; ++t) {
        int nd = n0 + t;
        if (nd < N) {
            float x0 = x[3*nd], x1 = x[3*nd+1], x2 = x[3*nd+2];
            float nj = fmaxf(fmaf(x2, Wn[128+lane], fmaf(x1, Wn[64+lane], fmaf(x0, Wn[lane], bn[lane]))), 0.f);
            nb16[(size_t)nd*64 + lane] = rnbf(nj);
        }
    }
    // A-fragment from own node's n features
    int node = n0 + m; if (node >= N) node = N - 1;
    float x0 = x[3*node], x1 = x[3*node+1], x2 = x[3*node+2];
    short8 ah[2], al[2];
    #pragma unroll
    for (int ks = 0; ks < 2; ++ks) {
        #pragma unroll
        for (int i = 0; i < 8; ++i) {
            int f = ks*32 + q*8 + i;
            float nf = fmaxf(fmaf(x2, Wn[128+f], fmaf(x1, Wn[64+f], fmaf(x0, Wn[f], bn[f]))), 0.f);
            unsigned short hb = rnbf(nf);
            ah[ks][i] = (short)hb;
            al[ks][i] = (short)rnbf(nf - bf2f(hb));
        }
    }
    floatx4 acc[4];
    #pragma unroll
    for (int jt = 0; jt < 4; ++jt) acc[jt] = (floatx4){0.f,0.f,0.f,0.f};
    #pragma unroll
    for (int ks = 0; ks < 2; ++ks) {
        int unit = 40 + ks;
        #pragma unroll
        for (int jt = 0; jt < 4; ++jt) {
            const unsigned short* qp = wpk + (((size_t)unit*4 + jt)*64 + lane)*16;
            short8 bh = *(const short8*)qp;
            short8 bl = *(const short8*)(qp + 8);
            acc[jt] = __builtin_amdgcn_mfma_f32_16x16x32_bf16(ah[ks], bh, acc[jt], 0,0,0);
            acc[jt] = __builtin_amdgcn_mfma_f32_16x16x32_bf16(ah[ks], bl, acc[jt], 0,0,0);
            acc[jt] = __builtin_amdgcn_mfma_f32_16x16x32_bf16(al[ks], bh, acc[jt], 0,0,0);
        }
    }
    #pragma unroll
    for (int jt = 0; jt < 4; ++jt) {
        float bb = b1[jt*16 + m];
        #pragma unroll
        for (int t = 0; t < 4; ++t) {
            int row = n0 + q*4 + t;
            if (row < N) acc1[(size_t)row*64 + jt*16 + m] = acc[jt][t] + bb;
        }
    }
}

// ---------- phase-1 mega-kernel: enc blocks || bucket-count blocks ----------
__global__ __launch_bounds__(256) void k_phase1(
    const float* __restrict__ x,
    const float* __restrict__ Wn, const float* __restrict__ bn,
    const unsigned short* __restrict__ wpk, const float* __restrict__ b1,
    float* __restrict__ acc1, unsigned short* __restrict__ nb16, int N,
    const int* __restrict__ ei, int* __restrict__ bktCnt, int E, int nbkt,
    int encBlocks, int cntBlocks)
{
    int bid = (int)blockIdx.x;
    if (bid < encBlocks) {
        dev_enc(x, Wn, bn, wpk, b1, acc1, nb16, N, bid);
    } else {
        dev_cnt(ei, bktCnt, E, nbkt, bid - encBlocks, cntBlocks);
    }
}

// pass A: local scan of bktCnt gives bucket bases; reserve runs via cursorRel.
__global__ __launch_bounds__(256) void k_partA(
    const int* __restrict__ ei, const float* __restrict__ ea,
    const int* __restrict__ et, const int* __restrict__ bktCnt,
    int* __restrict__ cursorRel, int2* __restrict__ tmp, int E, int nbkt)
{
    __shared__ int cnt[512], base[512], gbase[256];
    __shared__ int ts[256];
    int t = threadIdx.x;
    {
        int v = (t < nbkt) ? bktCnt[t] : 0;
        ts[t] = v; __syncthreads();
        for (int o = 1; o < 256; o <<= 1) {
            int add = (t >= o) ? ts[t-o] : 0;
            __syncthreads();
            ts[t] += add;
            __syncthreads();
        }
        gbase[t] = ts[t] - v;
    }
    int b0 = blockIdx.x * PA_CH;
    for (int j = t; j < nbkt; j += 256) cnt[j] = 0;
    __syncthreads();
    int2 rec[16]; int bk[16];
    #pragma unroll
    for (int u = 0; u < 16; ++u) {
        int e = b0 + u*256 + t;
        bk[u] = -1;
        if (e < E) {
            int rel = et[e];
            int src = ei[e];
            int dst = ei[E + e];
            float2 a = ((const float2*)ea)[e];
            rec[u] = make_int2(src | (rel << 17) | ((dst & 511) << 20),
                               ((int)rnbf(a.x) << 16) | (int)rnbf(a.y));
            bk[u] = dst >> 9;
            atomicAdd(&cnt[bk[u]], 1);
        }
    }
    __syncthreads();
    for (int j = t; j < nbkt; j += 256) {
        int c = cnt[j];
        base[j] = c ? (gbase[j] + atomicAdd(&cursorRel[j], c)) : 0;
    }
    __syncthreads();
    for (int j = t; j < nbkt; j += 256) cnt[j] = 0;
    __syncthreads();
    #pragma unroll
    for (int u = 0; u < 16; ++u) {
        if (bk[u] >= 0) {
            int pos = base[bk[u]] + atomicAdd(&cnt[bk[u]], 1);
            tmp[pos] = rec[u];
        }
    }
}
// pass B2: one block per bucket; off8 + exact placement.
__global__ __launch_bounds__(256) void k_partB2(
    const int2* __restrict__ tmp, const int* __restrict__ bktCnt,
    int* __restrict__ off8, int2* __restrict__ srec, int K8, int nbkt)
{
    __shared__ int cnt[PB_KEYS];
    __shared__ int ts[256];
    __shared__ int sb[2];
    int b = blockIdx.x;
    int t = threadIdx.x;
    {
        int v = (t < nbkt) ? bktCnt[t] : 0;
        ts[t] = v; __syncthreads();
        for (int o = 1; o < 256; o <<= 1) {
            int add = (t >= o) ? ts[t-o] : 0;
            __syncthreads();
            ts[t] += add;
            __syncthreads();
        }
        if (t == b) { sb[0] = ts[t] - v; sb[1] = ts[t]; }
    }
    __syncthreads();
    int bstart = sb[0];
    int bend = sb[1];
    int kbase = b * PB_KEYS;
    int kend = kbase + PB_KEYS; if (kend > K8) kend = K8;
    int nk = kend - kbase;
    for (int j = t; j < PB_KEYS; j += 256) cnt[j] = 0;
    __syncthreads();
    for (int i = bstart + t; i < bend; i += 256) {
        unsigned xw = (unsigned)tmp[i].x;
        int key = (int)((xw >> 20) & 511u)*8 + (int)((xw >> 17) & 7u);
        atomicAdd(&cnt[key], 1);
    }
    __syncthreads();
    int loc[16]; int lsum = 0;
    #pragma unroll
    for (int u = 0; u < 16; ++u) { loc[u] = cnt[t*16 + u]; lsum += loc[u]; }
    ts[t] = lsum; __syncthreads();
    for (int o = 1; o < 256; o <<= 1) {
        int add = (t >= o) ? ts[t-o] : 0;
        __syncthreads();
        ts[t] += add;
        __syncthreads();
    }
    int excl = ts[t] - lsum + bstart;
    #pragma unroll
    for (int u = 0; u < 16; ++u) {
        int j = t*16 + u;
        cnt[j] = excl;
        if (j < nk) off8[kbase + j] = excl;
        excl += loc[u];
    }
    if (t == 0 && kend == K8) off8[K8] = bend;
    __syncthreads();
    for (int i = bstart + t; i < bend; i += 256) {
        int2 r = tmp[i];
        unsigned xw = (unsigned)r.x;
        int src = (int)(xw & 0x1FFFFu);
        int rel = (int)((xw >> 17) & 7u);
        int key = (int)((xw >> 20) & 511u)*8 + rel;
        int pos = atomicAdd(&cnt[key], 1);
        srec[pos] = make_int2(src | (rel << 24), r.y);
    }
}

// ---------- pack weights into MFMA B-fragment order, split bf16 hi/lo ----------
// units: [0,16)=W1A rel=u>>1,ks=u&1 rows0..63; [16,32)=W2; [32,40)=W1B rows64..95;
//        [40,42)=Wroot1; [42,44)=Wroot2; [44,48)=Wagg (K=128)
__global__ __launch_bounds__(64) void k_wpack(
    const float* __restrict__ W1, const float* __restrict__ W2,
    const float* __restrict__ Wroot1, const float* __restrict__ Wroot2,
    const float* __restrict__ Wagg, unsigned short* __restrict__ wpk)
{
    int unit = blockIdx.x >> 2;
    int jt = blockIdx.x & 3;
    int lane = threadIdx.x;
    const float* Wb;
    int kbase;
    if (unit < 16) {
        Wb = W1 + (size_t)(unit >> 1)*96*64;
        kbase = (unit & 1)*32;
    } else if (unit < 32) {
        Wb = W2 + (size_t)((unit - 16) >> 1)*64*64;
        kbase = ((unit - 16) & 1)*32;
    } else if (unit < 40) {
        Wb = W1 + (size_t)(unit - 32)*96*64;
        kbase = 64;
    } else if (unit < 42) {
        Wb = Wroot1; kbase = (unit - 40)*32;
    } else if (unit < 44) {
        Wb = Wroot2; kbase = (unit - 42)*32;
    } else {
        Wb = Wagg;   kbase = (unit - 44)*32;
    }
    int j = jt*16 + (lane & 15);
    size_t base = (((size_t)unit*4 + jt)*64 + lane)*16;
    #pragma unroll
    for (int i = 0; i < 8; ++i) {
        int k = kbase + (lane >> 4)*8 + i;
        float f = Wb[(size_t)k*64 + j];
        unsigned short hi = rnbf(f);
        unsigned short lo = rnbf(f - bf2f(hi));
        wpk[base + i] = hi;
        wpk[base + 8 + i] = lo;
    }
}

// ---------- fallback: encoder (writes nbuf float) ----------
__global__ __launch_bounds__(256) void k_encB(
    const float* __restrict__ x,
    const float* __restrict__ Wn, const float* __restrict__ bn,
    const unsigned short* __restrict__ wpk, const float* __restrict__ b1,
    float* __restrict__ nbuf, float* __restrict__ acc1, int N)
{
    int lane = threadIdx.x & 63;
    int wave = threadIdx.x >> 6;
    int n0 = blockIdx.x*64 + 16*wave;
    int m = lane & 15, q = lane >> 4;
    #pragma unroll 4
    for (int t = 0; t < 16; ++t) {
        int nd = n0 + t;
        if (nd < N) {
            float x0 = x[3*nd], x1 = x[3*nd+1], x2 = x[3*nd+2];
            float nj = fmaxf(fmaf(x2, Wn[128+lane], fmaf(x1, Wn[64+lane], fmaf(x0, Wn[lane], bn[lane]))), 0.f);
            nbuf[(size_t)nd*64 + lane] = nj;
        }
    }
    int node = n0 + m; if (node >= N) node = N - 1;
    float x0 = x[3*node], x1 = x[3*node+1], x2 = x[3*node+2];
    short8 ah[2], al[2];
    #pragma unroll
    for (int ks = 0; ks < 2; ++ks) {
        #pragma unroll
        for (int i = 0; i < 8; ++i) {
            int f = ks*32 + q*8 + i;
            float nf = fmaxf(fmaf(x2, Wn[128+f], fmaf(x1, Wn[64+f], fmaf(x0, Wn[f], bn[f]))), 0.f);
            unsigned short hb = rnbf(nf);
            ah[ks][i] = (short)hb;
            al[ks][i] = (short)rnbf(nf - bf2f(hb));
        }
    }
    floatx4 acc[4];
    #pragma unroll
    for (int jt = 0; jt < 4; ++jt) acc[jt] = (floatx4){0.f,0.f,0.f,0.f};
    #pragma unroll
    for (int ks = 0; ks < 2; ++ks) {
        int unit = 40 + ks;
        #pragma unroll
        for (int jt = 0; jt < 4; ++jt) {
            const unsigned short* qp = wpk + (((size_t)unit*4 + jt)*64 + lane)*16;
            short8 bh = *(const short8*)qp;
            short8 bl = *(const short8*)(qp + 8);
            acc[jt] = __builtin_amdgcn_mfma_f32_16x16x32_bf16(ah[ks], bh, acc[jt], 0,0,0);
            acc[jt] = __builtin_amdgcn_mfma_f32_16x16x32_bf16(ah[ks], bl, acc[jt], 0,0,0);
            acc[jt] = __builtin_amdgcn_mfma_f32_16x16x32_bf16(al[ks], bh, acc[jt], 0,0,0);
        }
    }
    #pragma unroll
    for (int jt = 0; jt < 4; ++jt) {
        float bb = b1[jt*16 + m];
        #pragma unroll
        for (int t = 0; t < 4; ++t) {
            int row = n0 + q*4 + t;
            if (row < N) acc1[(size_t)row*64 + jt*16 + m] = acc[jt][t] + bb;
        }
    }
}

// ---------- fallback dense GEMM via MFMA split-bf16, bf16 output ----------
__global__ __launch_bounds__(256) void k_vgemmB(
    const float* __restrict__ F, const unsigned short* __restrict__ wpk,
    int unitBase, int g0, int Gc, unsigned short* __restrict__ Vbf,
    size_t plane, int N)
{
    int lane = threadIdx.x & 63;
    int wave = threadIdx.x >> 6;
    int n0 = blockIdx.x*64 + 16*wave;
    int m = lane & 15, q = lane >> 4;
    int node = n0 + m;
    if (node >= N) node = N - 1;
    const float4* Fr = (const float4*)(F + (size_t)node*64);
    short8 ah[2], al[2];
    #pragma unroll
    for (int ks = 0; ks < 2; ++ks) {
        float4 u0 = Fr[ks*8 + q*2];
        float4 u1 = Fr[ks*8 + q*2 + 1];
        float fv[8] = {u0.x,u0.y,u0.z,u0.w,u1.x,u1.y,u1.z,u1.w};
        #pragma unroll
        for (int i = 0; i < 8; ++i) {
            unsigned short hb = rnbf(fv[i]);
            ah[ks][i] = (short)hb;
            al[ks][i] = (short)rnbf(fv[i] - bf2f(hb));
        }
    }
    for (int p = 0; p < Gc; ++p) {
        int rel = g0 + p;
        floatx4 acc[4];
        #pragma unroll
        for (int jt = 0; jt < 4; ++jt) acc[jt] = (floatx4){0.f,0.f,0.f,0.f};
        #pragma unroll
        for (int ks = 0; ks < 2; ++ks) {
            int unit = unitBase + rel*2 + ks;
            #pragma unroll
            for (int jt = 0; jt < 4; ++jt) {
                const unsigned short* qp = wpk + (((size_t)unit*4 + jt)*64 + lane)*16;
                short8 bh = *(const short8*)qp;
                short8 bl = *(const short8*)(qp + 8);
                acc[jt] = __builtin_amdgcn_mfma_f32_16x16x32_bf16(ah[ks], bh, acc[jt], 0,0,0);
                acc[jt] = __builtin_amdgcn_mfma_f32_16x16x32_bf16(ah[ks], bl, acc[jt], 0,0,0);
                acc[jt] = __builtin_amdgcn_mfma_f32_16x16x32_bf16(al[ks], bh, acc[jt], 0,0,0);
            }
        }
        unsigned short* Vp = Vbf + (size_t)p*plane;
        #pragma unroll
        for (int jt = 0; jt < 4; ++jt) {
            #pragma unroll
            for (int t = 0; t < 4; ++t) {
                int row = n0 + q*4 + t;
                if (row < N) Vp[(size_t)row*64 + jt*16 + m] = rnbf(acc[jt][t]);
            }
        }
    }
}

// ---------- layer-1 NEW (G==8): flat walk, gather from 12.8MB bf16 n-table.
// Produces per-(node,rel) n-sums (nsum, bf16 [N][8][64]) + edge-MLP sums (Sep).
__global__ __launch_bounds__(256) void k_agg1n(
    const int2* __restrict__ srec, const int* __restrict__ off8,
    const unsigned short* __restrict__ nb16,
    const float* __restrict__ We, const float* __restrict__ be,
    unsigned short* __restrict__ nsum, unsigned short* __restrict__ Sep, int N)
{
    int lane = threadIdx.x & 63;
    int wv = threadIdx.x >> 6;
    float we0 = We[lane & 31], we1 = We[32 + (lane & 31)], bev = be[lane & 31];
    int stride = gridDim.x*4;
    for (int node = blockIdx.x*4 + wv; node < N; node += stride) {
        const int* ofp = off8 + node*8;
        int o0 = rfl(ofp[0]), o8 = rfl(ofp[8]);
        float ns0=0,ns1=0,ns2=0,ns3=0,ns4=0,ns5=0,ns6=0,ns7=0;
        int i = o0;
        for (; i + 16 <= o8; i += 16) {
            int2 q[16];
            #pragma unroll
            for (int u = 0; u < 16; ++u) q[u] = srec[i+u];
            int xs[16];
            #pragma unroll
            for (int u = 0; u < 16; ++u) xs[u] = rfl(q[u].x);
            float v[16];
            #pragma unroll
            for (int u = 0; u < 16; ++u)
                v[u] = bf2f(nb16[(unsigned)(xs[u] & 0xFFFFFF)*64u + (unsigned)lane]);
            #pragma unroll
            for (int u = 0; u < 16; ++u)
                acc8((int)(((unsigned)xs[u] >> 24) & 7u), v[u],
                     ns0,ns1,ns2,ns3,ns4,ns5,ns6,ns7);
        }
        for (; i + 8 <= o8; i += 8) {
            int2 q0 = srec[i+0], q1 = srec[i+1], q2 = srec[i+2], q3 = srec[i+3];
            int2 q4 = srec[i+4], q5 = srec[i+5], q6 = srec[i+6], q7 = srec[i+7];
            int x0 = rfl(q0.x), x1 = rfl(q1.x), x2 = rfl(q2.x), x3 = rfl(q3.x);
            int x4 = rfl(q4.x), x5 = rfl(q5.x), x6 = rfl(q6.x), x7 = rfl(q7.x);
            float v0 = bf2f(nb16[(unsigned)(x0 & 0xFFFFFF)*64u + (unsigned)lane]);
            float v1 = bf2f(nb16[(unsigned)(x1 & 0xFFFFFF)*64u + (unsigned)lane]);
            float v2 = bf2f(nb16[(unsigned)(x2 & 0xFFFFFF)*64u + (unsigned)lane]);
            float v3 = bf2f(nb16[(unsigned)(x3 & 0xFFFFFF)*64u + (unsigned)lane]);
            float v4 = bf2f(nb16[(unsigned)(x4 & 0xFFFFFF)*64u + (unsigned)lane]);
            float v5 = bf2f(nb16[(unsigned)(x5 & 0xFFFFFF)*64u + (unsigned)lane]);
            float v6 = bf2f(nb16[(unsigned)(x6 & 0xFFFFFF)*64u + (unsigned)lane]);
            float v7 = bf2f(nb16[(unsigned)(x7 & 0xFFFFFF)*64u + (unsigned)lane]);
            acc8((int)(((unsigned)x0 >> 24) & 7u), v0, ns0,ns1,ns2,ns3,ns4,ns5,ns6,ns7);
            acc8((int)(((unsigned)x1 >> 24) & 7u), v1, ns0,ns1,ns2,ns3,ns4,ns5,ns6,ns7);
            acc8((int)(((unsigned)x2 >> 24) & 7u), v2, ns0,ns1,ns2,ns3,ns4,ns5,ns6,ns7);
            acc8((int)(((unsigned)x3 >> 24) & 7u), v3, ns0,ns1,ns2,ns3,ns4,ns5,ns6,ns7);
            acc8((int)(((unsigned)x4 >> 24) & 7u), v4, ns0,ns1,ns2,ns3,ns4,ns5,ns6,ns7);
            acc8((int)(((unsigned)x5 >> 24) & 7u), v5, ns0,ns1,ns2,ns3,ns4,ns5,ns6,ns7);
            acc8((int)(((unsigned)x6 >> 24) & 7u), v6, ns0,ns1,ns2,ns3,ns4,ns5,ns6,ns7);
            acc8((int)(((unsigned)x7 >> 24) & 7u), v7, ns0,ns1,ns2,ns3,ns4,ns5,ns6,ns7);
        }
        for (; i < o8; ++i) {
            int xx = rfl(srec[i].x);
            float v = bf2f(nb16[(unsigned)(xx & 0xFFFFFF)*64u + (unsigned)lane]);
            acc8((int)(((unsigned)xx >> 24) & 7u), v, ns0,ns1,ns2,ns3,ns4,ns5,ns6,ns7);
        }
        // ---- sweep B: per-rel edge-MLP sums over L1-hot srec.y ----
        int o1 = rfl(ofp[1]), o2 = rfl(ofp[2]), o3 = rfl(ofp[3]), o4 = rfl(ofp[4]);
        int o5 = rfl(ofp[5]), o6 = rfl(ofp[6]), o7 = rfl(ofp[7]);
        const unsigned* sy = (const unsigned*)srec;
        float se0=0,se1=0,se2=0,se3=0,se4=0,se5=0,se6=0,se7=0;
        #pragma unroll
        for (int r = 0; r < 8; ++r) {
            int s = (r==0)?o0:(r==1)?o1:(r==2)?o2:(r==3)?o3:(r==4)?o4:(r==5)?o5:(r==6)?o6:o7;
            int e = (r==0)?o1:(r==1)?o2:(r==2)?o3:(r==3)?o4:(r==4)?o5:(r==5)?o6:(r==6)?o7:o8;
            if (s == e) continue;
            float ev = 0.f;
            int k = s;
            for (; k + 4 <= e; k += 4) {
                unsigned y0 = sy[2*(k+0)+1], y1 = sy[2*(k+1)+1];
                unsigned y2 = sy[2*(k+2)+1], y3 = sy[2*(k+3)+1];
                ev += eAct(y0, we0, we1, bev);
                ev += eAct(y1, we0, we1, bev);
                ev += eAct(y2, we0, we1, bev);
                ev += eAct(y3, we0, we1, bev);
            }
            for (; k < e; ++k) ev += eAct(sy[2*k+1], we0, we1, bev);
            if (r == 0) se0 = ev;  if (r == 1) se1 = ev;
            if (r == 2) se2 = ev;  if (r == 3) se3 = ev;
            if (r == 4) se4 = ev;  if (r == 5) se5 = ev;
            if (r == 6) se6 = ev;  if (r == 7) se7 = ev;
        }
        // nsum store: [node][rel][64] bf16 (always, zeros for empty rels)
        unsigned short* np = nsum + (size_t)node*512;
        np[0*64 + lane] = rnbf(ns0);
        np[1*64 + lane] = rnbf(ns1);
        np[2*64 + lane] = rnbf(ns2);
        np[3*64 + lane] = rnbf(ns3);
        np[4*64 + lane] = rnbf(ns4);
        np[5*64 + lane] = rnbf(ns5);
        np[6*64 + lane] = rnbf(ns6);
        np[7*64 + lane] = rnbf(ns7);
        // Se store: [node][rel][32] bf16; lanes<32 even rel, >=32 odd rel
        unsigned short* Sp = Sep + (size_t)node*256;
        Sp[0*64 + lane] = rnbf((lane < 32) ? se0 : se1);
        Sp[1*64 + lane] = rnbf((lane < 32) ? se2 : se3);
        Sp[2*64 + lane] = rnbf((lane < 32) ? se4 : se5);
        Sp[3*64 + lane] = rnbf((lane < 32) ? se6 : se7);
    }
}

// ---------- NEW: gemm1 = acc1 += sum_r nsum[r]@W1A[r] + sum_r Se[r]@W1B[r] ----------
__global__ __launch_bounds__(256) void k_gemm1(
    const unsigned short* __restrict__ nsum, const unsigned short* __restrict__ Sep,
    const unsigned short* __restrict__ wpk, float* __restrict__ acc1, int N)
{
    int lane = threadIdx.x & 63;
    int wave = threadIdx.x >> 6;
    int n0 = blockIdx.x*64 + 16*wave;
    int m = lane & 15, q = lane >> 4;
    int node = n0 + m;
    if (node >= N) node = N - 1;
    floatx4 acc[4];
    #pragma unroll
    for (int jt = 0; jt < 4; ++jt) acc[jt] = (floatx4){0.f,0.f,0.f,0.f};
    for (int rel = 0; rel < 8; ++rel) {
        // n-part: units rel*2+ks (W1 rows 0..63)
        #pragma unroll
        for (int ks = 0; ks < 2; ++ks) {
            short8 na = *(const short8*)(nsum + (size_t)node*512 + rel*64 + ks*32 + q*8);
            int unit = rel*2 + ks;
            #pragma unroll
            for (int jt = 0; jt < 4; ++jt) {
                const unsigned short* qp = wpk + (((size_t)unit*4 + jt)*64 + lane)*16;
                short8 bh = *(const short8*)qp;
                short8 bl = *(const short8*)(qp + 8);
                acc[jt] = __builtin_amdgcn_mfma_f32_16x16x32_bf16(na, bh, acc[jt], 0,0,0);
                acc[jt] = __builtin_amdgcn_mfma_f32_16x16x32_bf16(na, bl, acc[jt], 0,0,0);
            }
        }
        // e-part: unit 32+rel (W1 rows 64..95)
        short8 sa = *(const short8*)(Sep + (size_t)node*256 + rel*32 + q*8);
        int unit2 = 32 + rel;
        #pragma unroll
        for (int jt = 0; jt < 4; ++jt) {
            const unsigned short* qp = wpk + (((size_t)unit2*4 + jt)*64 + lane)*16;
            short8 bh = *(const short8*)qp;
            short8 bl = *(const short8*)(qp + 8);
            acc[jt] = __builtin_amdgcn_mfma_f32_16x16x32_bf16(sa, bh, acc[jt], 0,0,0);
            acc[jt] = __builtin_amdgcn_mfma_f32_16x16x32_bf16(sa, bl, acc[jt], 0,0,0);
        }
    }
    #pragma unroll
    for (int jt = 0; jt < 4; ++jt) {
        #pragma unroll
        for (int t = 0; t < 4; ++t) {
            int row = n0 + q*4 + t;
            if (row < N) acc1[(size_t)row*64 + jt*16 + m] += acc[jt][t];
        }
    }
}

// ---------- hrowV: h=relu(acc1) -> root2 (acc2) + 8 layer-2 U planes ----------
__global__ __launch_bounds__(256) void k_hrowV(
    const float* __restrict__ acc1, float* __restrict__ acc2,
    const unsigned short* __restrict__ wpk, const float* __restrict__ b2,
    unsigned short* __restrict__ Vbf, size_t plane, int N)
{
    int lane = threadIdx.x & 63;
    int wave = threadIdx.x >> 6;
    int n0 = blockIdx.x*64 + 16*wave;
    int m = lane & 15, q = lane >> 4;
    int node = n0 + m;
    if (node >= N) node = N - 1;
    const float4* Fr = (const float4*)(acc1 + (size_t)node*64);
    short8 ah[2], al[2];
    #pragma unroll
    for (int ks = 0; ks < 2; ++ks) {
        float4 u0 = Fr[ks*8 + q*2];
        float4 u1 = Fr[ks*8 + q*2 + 1];
        float fv[8] = {u0.x,u0.y,u0.z,u0.w,u1.x,u1.y,u1.z,u1.w};
        #pragma unroll
        for (int i = 0; i < 8; ++i) {
            float hv = fmaxf(fv[i], 0.f);
            unsigned short hb = rnbf(hv);
            ah[ks][i] = (short)hb;
            al[ks][i] = (short)rnbf(hv - bf2f(hb));
        }
    }
    // root2 -> acc2
    {
        floatx4 acc[4];
        #pragma unroll
        for (int jt = 0; jt < 4; ++jt) acc[jt] = (floatx4){0.f,0.f,0.f,0.f};
        #pragma unroll
        for (int ks = 0; ks < 2; ++ks) {
            int unit = 42 + ks;
            #pragma unroll
            for (int jt = 0; jt < 4; ++jt) {
                const unsigned short* qp = wpk + (((size_t)unit*4 + jt)*64 + lane)*16;
                short8 bh = *(const short8*)qp;
                short8 bl = *(const short8*)(qp + 8);
                acc[jt] = __builtin_amdgcn_mfma_f32_16x16x32_bf16(ah[ks], bh, acc[jt], 0,0,0);
                acc[jt] = __builtin_amdgcn_mfma_f32_16x16x32_bf16(ah[ks], bl, acc[jt], 0,0,0);
                acc[jt] = __builtin_amdgcn_mfma_f32_16x16x32_bf16(al[ks], bh, acc[jt], 0,0,0);
            }
        }
        #pragma unroll
        for (int jt = 0; jt < 4; ++jt) {
            float bb = b2[jt*16 + m];
            #pragma unroll
            for (int t = 0; t < 4; ++t) {
                int row = n0 + q*4 + t;
                if (row < N) acc2[(size_t)row*64 + jt*16 + m] = acc[jt][t] + bb;
            }
        }
    }
    // 8 U planes (unitBase=16)
    for (int p = 0; p < 8; ++p) {
        floatx4 acc[4];
        #pragma unroll
        for (int jt = 0; jt < 4; ++jt) acc[jt] = (floatx4){0.f,0.f,0.f,0.f};
        #pragma unroll
        for (int ks = 0; ks < 2; ++ks) {
            int unit = 16 + p*2 + ks;
            #pragma unroll
            for (int jt = 0; jt < 4; ++jt) {
                const unsigned short* qp = wpk + (((size_t)unit*4 + jt)*64 + lane)*16;
                short8 bh = *(const short8*)qp;
                short8 bl = *(const short8*)(qp + 8);
                acc[jt] = __builtin_amdgcn_mfma_f32_16x16x32_bf16(ah[ks], bh, acc[jt], 0,0,0);
                acc[jt] = __builtin_amdgcn_mfma_f32_16x16x32_bf16(ah[ks], bl, acc[jt], 0,0,0);
                acc[jt] = __builtin_amdgcn_mfma_f32_16x16x32_bf16(al[ks], bh, acc[jt], 0,0,0);
            }
        }
        unsigned short* Vp = Vbf + (size_t)p*plane;
        #pragma unroll
        for (int jt = 0; jt < 4; ++jt) {
            #pragma unroll
            for (int t = 0; t < 4; ++t) {
                int row = n0 + q*4 + t;
                if (row < N) Vp[(size_t)row*64 + jt*16 + m] = rnbf(acc[jt][t]);
            }
        }
    }
}

// ---------- fallback layer-1 kernels (G<8) ----------
__global__ __launch_bounds__(256) void k_agg1e(
    const int2* __restrict__ srec, const int* __restrict__ off8,
    const unsigned short* __restrict__ Vbf, size_t plane,
    const float* __restrict__ We, const float* __restrict__ be,
    float* __restrict__ acc1, unsigned short* __restrict__ Sep, int N, int Gc)
{
    int lane = threadIdx.x & 63;
    int wv = threadIdx.x >> 6;
    float we0 = We[lane & 31], we1 = We[32 + (lane & 31)], bev = be[lane & 31];
    int stride = gridDim.x*4;
    for (int node = blockIdx.x*4 + wv; node < N; node += stride) {
        int o0 = rfl(off8[node*8+0]), o1 = rfl(off8[node*8+1]), o2 = rfl(off8[node*8+2]);
        int o3 = rfl(off8[node*8+3]), o4 = rfl(off8[node*8+4]), o5 = rfl(off8[node*8+5]);
        int o6 = rfl(off8[node*8+6]), o7 = rfl(off8[node*8+7]), o8 = rfl(off8[node*8+8]);
        float vsum = 0.f;
        float se0=0,se1=0,se2=0,se3=0,se4=0,se5=0,se6=0,se7=0;
        #pragma unroll
        for (int r = 0; r < 8; ++r) {
            int s = (r==0)?o0:(r==1)?o1:(r==2)?o2:(r==3)?o3:(r==4)?o4:(r==5)?o5:(r==6)?o6:o7;
            int e = (r==0)?o1:(r==1)?o2:(r==2)?o3:(r==3)?o4:(r==4)?o5:(r==5)?o6:(r==6)?o7:o8;
            if (s == e) continue;
            const unsigned short* Vp = Vbf + (size_t)r*plane;
            bool doV = (r < Gc);
            float ev = 0.f;
            int i = s;
            for (; i + 8 <= e; i += 8) {
                int2 q0 = srec[i+0], q1 = srec[i+1], q2 = srec[i+2], q3 = srec[i+3];
                int2 q4 = srec[i+4], q5 = srec[i+5], q6 = srec[i+6], q7 = srec[i+7];
                if (doV) {
                    float v0 = bf2f(Vp[(size_t)(rfl(q0.x) & 0xFFFFFF)*64 + lane]);
                    float v1 = bf2f(Vp[(size_t)(rfl(q1.x) & 0xFFFFFF)*64 + lane]);
                    float v2 = bf2f(Vp[(size_t)(rfl(q2.x) & 0xFFFFFF)*64 + lane]);
                    float v3 = bf2f(Vp[(size_t)(rfl(q3.x) & 0xFFFFFF)*64 + lane]);
                    float v4 = bf2f(Vp[(size_t)(rfl(q4.x) & 0xFFFFFF)*64 + lane]);
                    float v5 = bf2f(Vp[(size_t)(rfl(q5.x) & 0xFFFFFF)*64 + lane]);
                    float v6 = bf2f(Vp[(size_t)(rfl(q6.x) & 0xFFFFFF)*64 + lane]);
                    float v7 = bf2f(Vp[(size_t)(rfl(q7.x) & 0xFFFFFF)*64 + lane]);
                    vsum += ((v0+v1)+(v2+v3)) + ((v4+v5)+(v6+v7));
                }
                ev += eAct((unsigned)q0.y, we0, we1, bev);
                ev += eAct((unsigned)q1.y, we0, we1, bev);
                ev += eAct((unsigned)q2.y, we0, we1, bev);
                ev += eAct((unsigned)q3.y, we0, we1, bev);
                ev += eAct((unsigned)q4.y, we0, we1, bev);
                ev += eAct((unsigned)q5.y, we0, we1, bev);
                ev += eAct((unsigned)q6.y, we0, we1, bev);
                ev += eAct((unsigned)q7.y, we0, we1, bev);
            }
            for (; i < e; ++i) {
                int2 qq = srec[i];
                if (doV) vsum += bf2f(Vp[(size_t)(rfl(qq.x) & 0xFFFFFF)*64 + lane]);
                ev += eAct((unsigned)qq.y, we0, we1, bev);
            }
            if (r == 0) se0 = ev;  if (r == 1) se1 = ev;
            if (r == 2) se2 = ev;  if (r == 3) se3 = ev;
            if (r == 4) se4 = ev;  if (r == 5) se5 = ev;
            if (r == 6) se6 = ev;  if (r == 7) se7 = ev;
        }
        unsigned short* Sp = Sep + (size_t)node*256;
        Sp[0*64 + lane] = rnbf((lane < 32) ? se0 : se1);
        Sp[1*64 + lane] = rnbf((lane < 32) ? se2 : se3);
        Sp[2*64 + lane] = rnbf((lane < 32) ? se4 : se5);
        Sp[3*64 + lane] = rnbf((lane < 32) ? se6 : se7);
        if (o0 != o8) acc1[(size_t)node*64 + lane] += vsum;
    }
}
__global__ __launch_bounds__(256) void k_agg1v(
    const int2* __restrict__ srec, const int* __restrict__ off8,
    const unsigned short* __restrict__ Vbf, size_t plane,
    float* __restrict__ acc1, int N, int g0, int g1)
{
    int lane = threadIdx.x & 63;
    int wv = threadIdx.x >> 6;
    int stride = gridDim.x*4;
    for (int node = blockIdx.x*4 + wv; node < N; node += stride) {
        float vsum = 0.f;
        bool any = false;
        for (int r = g0; r < g1; ++r) {
            int s = rfl(off8[node*8 + r]);
            int e = rfl(off8[node*8 + r + 1]);
            if (s == e) continue;
            any = true;
            const unsigned short* Vp = Vbf + (size_t)(r - g0)*plane;
            int i = s;
            for (; i + 8 <= e; i += 8) {
                int s0 = rfl(srec[i+0].x) & 0xFFFFFF, s1 = rfl(srec[i+1].x) & 0xFFFFFF;
                int s2 = rfl(srec[i+2].x) & 0xFFFFFF, s3 = rfl(srec[i+3].x) & 0xFFFFFF;
                int s4 = rfl(srec[i+4].x) & 0xFFFFFF, s5 = rfl(srec[i+5].x) & 0xFFFFFF;
                int s6 = rfl(srec[i+6].x) & 0xFFFFFF, s7 = rfl(srec[i+7].x) & 0xFFFFFF;
                float v0 = bf2f(Vp[(size_t)s0*64 + lane]), v1 = bf2f(Vp[(size_t)s1*64 + lane]);
                float v2 = bf2f(Vp[(size_t)s2*64 + lane]), v3 = bf2f(Vp[(size_t)s3*64 + lane]);
                float v4 = bf2f(Vp[(size_t)s4*64 + lane]), v5 = bf2f(Vp[(size_t)s5*64 + lane]);
                float v6 = bf2f(Vp[(size_t)s6*64 + lane]), v7 = bf2f(Vp[(size_t)s7*64 + lane]);
                vsum += ((v0+v1)+(v2+v3)) + ((v4+v5)+(v6+v7));
            }
            for (; i < e; ++i) {
                int sx = rfl(srec[i].x) & 0xFFFFFF;
                vsum += bf2f(Vp[(size_t)sx*64 + lane]);
            }
        }
        if (any) acc1[(size_t)node*64 + lane] += vsum;
    }
}
__global__ __launch_bounds__(256) void k_segemm(
    const unsigned short* __restrict__ Sep, const unsigned short* __restrict__ wpk,
    float* __restrict__ acc1, int N)
{
    int lane = threadIdx.x & 63;
    int wave = threadIdx.x >> 6;
    int n0 = blockIdx.x*64 + 16*wave;
    int m = lane & 15, q = lane >> 4;
    int node = n0 + m;
    if (node >= N) node = N - 1;
    floatx4 acc[4];
    #pragma unroll
    for (int jt = 0; jt < 4; ++jt) acc[jt] = (floatx4){0.f,0.f,0.f,0.f};
    for (int rel = 0; rel < 8; ++rel) {
        short8 ah = *(const short8*)(Sep + (size_t)node*256 + rel*32 + q*8);
        int unit = 32 + rel;
        #pragma unroll
        for (int jt = 0; jt < 4; ++jt) {
            const unsigned short* qp = wpk + (((size_t)unit*4 + jt)*64 + lane)*16;
            short8 bh = *(const short8*)qp;
            short8 bl = *(const short8*)(qp + 8);
            acc[jt] = __builtin_amdgcn_mfma_f32_16x16x32_bf16(ah, bh, acc[jt], 0,0,0);
            acc[jt] = __builtin_amdgcn_mfma_f32_16x16x32_bf16(ah, bl, acc[jt], 0,0,0);
        }
    }
    #pragma unroll
    for (int jt = 0; jt < 4; ++jt) {
        #pragma unroll
        for (int t = 0; t < 4; ++t) {
            int row = n0 + q*4 + t;
            if (row < N) acc1[(size_t)row*64 + jt*16 + m] += acc[jt][t];
        }
    }
}
__global__ __launch_bounds__(256) void k_hrowB(
    float* __restrict__ acc1, float* __restrict__ acc2,
    const unsigned short* __restrict__ wpk, const float* __restrict__ b2, int N)
{
    int lane = threadIdx.x & 63;
    int wave = threadIdx.x >> 6;
    int n0 = blockIdx.x*64 + 16*wave;
    int m = lane & 15, q = lane >> 4;
    int node = n0 + m;
    if (node >= N) node = N - 1;
    float4* Fr = (float4*)(acc1 + (size_t)node*64);
    short8 ah[2], al[2];
    #pragma unroll
    for (int ks = 0; ks < 2; ++ks) {
        float4 u0 = Fr[ks*8 + q*2];
        float4 u1 = Fr[ks*8 + q*2 + 1];
        float fv[8] = {u0.x,u0.y,u0.z,u0.w,u1.x,u1.y,u1.z,u1.w};
        #pragma unroll
        for (int i = 0; i < 8; ++i) {
            float hv = fmaxf(fv[i], 0.f);
            fv[i] = hv;
            unsigned short hb = rnbf(hv);
            ah[ks][i] = (short)hb;
            al[ks][i] = (short)rnbf(hv - bf2f(hb));
        }
        Fr[ks*8 + q*2]     = make_float4(fv[0], fv[1], fv[2], fv[3]);
        Fr[ks*8 + q*2 + 1] = make_float4(fv[4], fv[5], fv[6], fv[7]);
    }
    floatx4 acc[4];
    #pragma unroll
    for (int jt = 0; jt < 4; ++jt) acc[jt] = (floatx4){0.f,0.f,0.f,0.f};
    #pragma unroll
    for (int ks = 0; ks < 2; ++ks) {
        int unit = 42 + ks;
        #pragma unroll
        for (int jt = 0; jt < 4; ++jt) {
            const unsigned short* qp = wpk + (((size_t)unit*4 + jt)*64 + lane)*16;
            short8 bh = *(const short8*)qp;
            short8 bl = *(const short8*)(qp + 8);
            acc[jt] = __builtin_amdgcn_mfma_f32_16x16x32_bf16(ah[ks], bh, acc[jt], 0,0,0);
            acc[jt] = __builtin_amdgcn_mfma_f32_16x16x32_bf16(ah[ks], bl, acc[jt], 0,0,0);
            acc[jt] = __builtin_amdgcn_mfma_f32_16x16x32_bf16(al[ks], bh, acc[jt], 0,0,0);
        }
    }
    #pragma unroll
    for (int jt = 0; jt < 4; ++jt) {
        float bb = b2[jt*16 + m];
        #pragma unroll
        for (int t = 0; t < 4; ++t) {
            int row = n0 + q*4 + t;
            if (row < N) acc2[(size_t)row*64 + jt*16 + m] = acc[jt][t] + bb;
        }
    }
}

// ---------- layer-2 (G==8 fast path): FLAT walk, 16-deep ----------
__global__ __launch_bounds__(256) void k_agg2f(
    const int2* __restrict__ srec, const int* __restrict__ off8,
    const unsigned short* __restrict__ Ubf, size_t plane,
    float* __restrict__ acc2, int N)
{
    int lane = threadIdx.x & 63;
    int wv = threadIdx.x >> 6;
    unsigned pl = (unsigned)plane;
    int stride = gridDim.x*4;
    for (int node = blockIdx.x*4 + wv; node < N; node += stride) {
        int o0 = rfl(off8[node*8]);
        int o8 = rfl(off8[node*8 + 8]);
        if (o0 == o8) continue;
        float add = 0.f, mx = 0.f;
        int cur = -1;
        int i = o0;
        for (; i + 16 <= o8; i += 16) {
            int2 q[16];
            #pragma unroll
            for (int u = 0; u < 16; ++u) q[u] = srec[i+u];
            int xs[16];
            #pragma unroll
            for (int u = 0; u < 16; ++u) xs[u] = rfl(q[u].x);
            float v[16];
            #pragma unroll
            for (int u = 0; u < 16; ++u) v[u] = bf2f(Ubf[vidx(xs[u], pl, lane)]);
            #pragma unroll
            for (int u = 0; u < 16; ++u)
                mstep((int)(((unsigned)xs[u] >> 24) & 7u), v[u], cur, mx, add);
        }
        for (; i + 8 <= o8; i += 8) {
            int2 q0 = srec[i+0], q1 = srec[i+1], q2 = srec[i+2], q3 = srec[i+3];
            int2 q4 = srec[i+4], q5 = srec[i+5], q6 = srec[i+6], q7 = srec[i+7];
            int x0 = rfl(q0.x), x1 = rfl(q1.x), x2 = rfl(q2.x), x3 = rfl(q3.x);
            int x4 = rfl(q4.x), x5 = rfl(q5.x), x6 = rfl(q6.x), x7 = rfl(q7.x);
            float v0 = bf2f(Ubf[vidx(x0, pl, lane)]);
            float v1 = bf2f(Ubf[vidx(x1, pl, lane)]);
            float v2 = bf2f(Ubf[vidx(x2, pl, lane)]);
            float v3 = bf2f(Ubf[vidx(x3, pl, lane)]);
            float v4 = bf2f(Ubf[vidx(x4, pl, lane)]);
            float v5 = bf2f(Ubf[vidx(x5, pl, lane)]);
            float v6 = bf2f(Ubf[vidx(x6, pl, lane)]);
            float v7 = bf2f(Ubf[vidx(x7, pl, lane)]);
            mstep((int)(((unsigned)x0 >> 24) & 7u), v0, cur, mx, add);
            mstep((int)(((unsigned)x1 >> 24) & 7u), v1, cur, mx, add);
            mstep((int)(((unsigned)x2 >> 24) & 7u), v2, cur, mx, add);
            mstep((int)(((unsigned)x3 >> 24) & 7u), v3, cur, mx, add);
            mstep((int)(((unsigned)x4 >> 24) & 7u), v4, cur, mx, add);
            mstep((int)(((unsigned)x5 >> 24) & 7u), v5, cur, mx, add);
            mstep((int)(((unsigned)x6 >> 24) & 7u), v6, cur, mx, add);
            mstep((int)(((unsigned)x7 >> 24) & 7u), v7, cur, mx, add);
        }
        for (; i < o8; ++i) {
            int xx = rfl(srec[i].x);
            float v = bf2f(Ubf[vidx(xx, pl, lane)]);
            mstep((int)(((unsigned)xx >> 24) & 7u), v, cur, mx, add);
        }
        add += mx;
        acc2[(size_t)node*64 + lane] += add;
    }
}

// ---------- layer-2 (fallback G<8) ----------
__global__ __launch_bounds__(256) void k_agg2(
    const int2* __restrict__ srec, const int* __restrict__ off8,
    const unsigned short* __restrict__ Ubf, size_t plane,
    float* __restrict__ acc2, int N, int g0, int g1)
{
    int lane = threadIdx.x & 63;
    int wv = threadIdx.x >> 6;
    int stride = gridDim.x*4;
    const float NEG = -__builtin_inff();
    for (int node = blockIdx.x*4 + wv; node < N; node += stride) {
        float add = 0.f;
        bool any = false;
        for (int r = g0; r < g1; ++r) {
            int s = rfl(off8[node*8 + r]);
            int e = rfl(off8[node*8 + r + 1]);
            if (s == e) continue;
            any = true;
            const unsigned short* Up = Ubf + (size_t)(r - g0)*plane;
            float mx = NEG;
            int i = s;
            for (; i + 8 <= e; i += 8) {
                int s0 = rfl(srec[i+0].x) & 0xFFFFFF, s1 = rfl(srec[i+1].x) & 0xFFFFFF;
                int s2 = rfl(srec[i+2].x) & 0xFFFFFF, s3 = rfl(srec[i+3].x) & 0xFFFFFF;
                int s4 = rfl(srec[i+4].x) & 0xFFFFFF, s5 = rfl(srec[i+5].x) & 0xFFFFFF;
                int s6 = rfl(srec[i+6].x) & 0xFFFFFF, s7 = rfl(srec[i+7].x) & 0xFFFFFF;
                float v0 = bf2f(Up[(size_t)s0*64 + lane]), v1 = bf2f(Up[(size_t)s1*64 + lane]);
                float v2 = bf2f(Up[(size_t)s2*64 + lane]), v3 = bf2f(Up[(size_t)s3*64 + lane]);
                float v4 = bf2f(Up[(size_t)s4*64 + lane]), v5 = bf2f(Up[(size_t)s5*64 + lane]);
                float v6 = bf2f(Up[(size_t)s6*64 + lane]), v7 = bf2f(Up[(size_t)s7*64 + lane]);
                float m01 = fmaxf(v0, v1), m23 = fmaxf(v2, v3);
                float m45 = fmaxf(v4, v5), m67 = fmaxf(v6, v7);
                mx = fmaxf(mx, fmaxf(fmaxf(m01, m23), fmaxf(m45, m67)));
            }
            for (; i < e; ++i) {
                int sx = rfl(srec[i].x) & 0xFFFFFF;
                mx = fmaxf(mx, bf2f(Up[(size_t)sx*64 + lane]));
            }
            add += mx;
        }
        if (any) acc2[(size_t)node*64 + lane] += add;
    }
}

// ---------- head via MFMA ----------
__global__ __launch_bounds__(256) void k_finB(
    const float* __restrict__ acc2, const float* __restrict__ omega,
    const float* __restrict__ Wo, const float* __restrict__ bo,
    const unsigned short* __restrict__ wpk,
    const float* __restrict__ bagg, const float* __restrict__ Wc,
    const float* __restrict__ bc, float* __restrict__ out, int N)
{
    int lane = threadIdx.x & 63;
    int wave = threadIdx.x >> 6;
    int n0 = blockIdx.x*64 + 16*wave;
    int m = lane & 15, q = lane >> 4;
    int node = n0 + m;
    if (node >= N) node = N - 1;
    short8 ah[4], al[4];
    const float4* Fr = (const float4*)(acc2 + (size_t)node*64);
    #pragma unroll
    for (int ks = 0; ks < 2; ++ks) {
        float4 u0 = Fr[ks*8 + q*2];
        float4 u1 = Fr[ks*8 + q*2 + 1];
        float fv[8] = {u0.x,u0.y,u0.z,u0.w,u1.x,u1.y,u1.z,u1.w};
        #pragma unroll
        for (int i = 0; i < 8; ++i) {
            float hv = fmaxf(fv[i], 0.f);
            unsigned short hb = rnbf(hv);
            ah[ks][i] = (short)hb;
            al[ks][i] = (short)rnbf(hv - bf2f(hb));
        }
    }
    float om0 = omega[2*node], om1 = omega[2*node+1];
    #pragma unroll
    for (int ks = 2; ks < 4; ++ks) {
        #pragma unroll
        for (int i = 0; i < 8; ++i) {
            int f = (ks - 2)*32 + q*8 + i;
            float ov = fmaxf(fmaf(om1, Wo[64+f], fmaf(om0, Wo[f], bo[f])), 0.f);
            unsigned short hb = rnbf(ov);
            ah[ks][i] = (short)hb;
            al[ks][i] = (short)rnbf(ov - bf2f(hb));
        }
    }
    floatx4 acc[4];
    #pragma unroll
    for (int jt = 0; jt < 4; ++jt) acc[jt] = (floatx4){0.f,0.f,0.f,0.f};
    #pragma unroll
    for (int ks = 0; ks < 4; ++ks) {
        int unit = 44 + ks;
        #pragma unroll
        for (int jt = 0; jt < 4; ++jt) {
            const unsigned short* qp = wpk + (((size_t)unit*4 + jt)*64 + lane)*16;
            short8 bh = *(const short8*)qp;
            short8 bl = *(const short8*)(qp + 8);
            acc[jt] = __builtin_amdgcn_mfma_f32_16x16x32_bf16(ah[ks], bh, acc[jt], 0,0,0);
            acc[jt] = __builtin_amdgcn_mfma_f32_16x16x32_bf16(ah[ks], bl, acc[jt], 0,0,0);
            acc[jt] = __builtin_amdgcn_mfma_f32_16x16x32_bf16(al[ks], bh, acc[jt], 0,0,0);
        }
    }
    float bg0 = bagg[m], bg1 = bagg[16+m], bg2 = bagg[32+m], bg3 = bagg[48+m];
    float wc0 = Wc[m],   wc1 = Wc[16+m],   wc2 = Wc[32+m],   wc3 = Wc[48+m];
    float bc0 = bc[0];
    #pragma unroll
    for (int t = 0; t < 4; ++t) {
        float s = fmaxf(acc[0][t] + bg0, 0.f)*wc0
                + fmaxf(acc[1][t] + bg1, 0.f)*wc1
                + fmaxf(acc[2][t] + bg2, 0.f)*wc2
                + fmaxf(acc[3][t] + bg3, 0.f)*wc3;
        s += __shfl_xor(s, 1);
        s += __shfl_xor(s, 2);
        s += __shfl_xor(s, 4);
        s += __shfl_xor(s, 8);
        int row = n0 + q*4 + t;
        if (m == 0 && row < N) out[row] = tanhf(s + bc0) * 5.0f;
    }
}

extern "C" void kernel_launch(void* const* d_in, const int* in_sizes, int n_in,
                              void* d_out, int out_size, void* d_ws, size_t ws_size,
                              hipStream_t stream)
{
    const float* x      = (const float*)d_in[0];
    const int*   ei     = (const int*)d_in[1];
    const float* ea     = (const float*)d_in[2];
    const int*   et     = (const int*)d_in[3];
    const float* omega  = (const float*)d_in[4];
    const float* Wn     = (const float*)d_in[5];
    const float* bn     = (const float*)d_in[6];
    const float* We     = (const float*)d_in[7];
    const float* be     = (const float*)d_in[8];
    const float* Wo     = (const float*)d_in[9];
    const float* bo     = (const float*)d_in[10];
    const float* W1     = (const float*)d_in[11];
    const float* Wroot1 = (const float*)d_in[12];
    const float* b1     = (const float*)d_in[13];
    const float* W2     = (const float*)d_in[14];
    const float* Wroot2 = (const float*)d_in[15];
    const float* b2     = (const float*)d_in[16];
    const float* Wagg   = (const float*)d_in[17];
    const float* bagg   = (const float*)d_in[18];
    const float* Wc     = (const float*)d_in[19];
    const float* bc     = (const float*)d_in[20];
    int N = in_sizes[0] / 3;
    int E = in_sizes[3];
    float* out = (float*)d_out;

    int K8 = N*8;
    int nb = (K8 + SCHUNK - 1)/SCHUNK;

    // ---- workspace layout: every carve 256B-aligned ----
    #define ALIGN256(p) ((char*)(((size_t)(p) + 255) & ~(size_t)255))
    char* pp = (char*)d_ws;
    float* nbuf   = (float*)pp;  pp = ALIGN256(pp + (size_t)N*64*4);     // n-table (bf16 fast / f32 fallback); reused as acc2
    float* acc1   = (float*)pp;  pp = ALIGN256(pp + (size_t)N*64*4);
    int2*  srec   = (int2*)pp;   pp = ALIGN256(pp + (size_t)E*8);
    int*   deg8   = (int*)pp;    pp = ALIGN256(pp + (size_t)K8*4);       // bktCnt(512)+cursorRel(512) fast path
    int*   off8   = (int*)pp;    pp = ALIGN256(pp + (size_t)(K8+1)*4);
    int*   cursor = (int*)pp;    pp = ALIGN256(pp + (size_t)K8*4);
    int*   bsum   = (int*)pp;    pp = ALIGN256(pp + (size_t)nb*4);
    unsigned short* wpk = (unsigned short*)pp;
    pp = ALIGN256(pp + (size_t)48*4*64*16*2);                            // 384 KB
    unsigned short* Sepool = (unsigned short*)pp;
    pp = ALIGN256(pp + (size_t)N*256*2);                                 // 51 MB
    size_t off = (size_t)(pp - (char*)d_ws);
    size_t planeElems = (size_t)N*64;
    size_t avail = (ws_size > off) ? (ws_size - off) : 0;
    int G = (int)(avail / (planeElems*2));
    if (G > 8) G = 8;
    if (G < 1) G = 1;
    unsigned short* Vbf = (unsigned short*)pp;   // fast: nsum (L1) then U planes (L2)
    float* acc2 = nbuf;
    unsigned short* nb16 = (unsigned short*)nbuf;

    int gblocks = (N + 63)/64;
    int nbkt = (N + 511) >> 9;
    bool fastSort = (N <= 131072) && ((size_t)E*8 <= (size_t)N*256*2);
    int* bktCnt = deg8;
    int* cursorRel = deg8 + 512;

    if (fastSort) hipMemsetAsync(deg8, 0, 4096, stream);
    else          hipMemsetAsync(deg8, 0, (size_t)K8*4, stream);
    k_wpack<<<192, 64, 0, stream>>>(W1, W2, Wroot1, Wroot2, Wagg, wpk);

    // ---- phase 1: encoder (+bucket count on fast sort) ----
    if (G == 8) {
        int cb = fastSort ? CNTB : 0;
        k_phase1<<<gblocks + cb, 256, 0, stream>>>(x, Wn, bn, wpk, b1, acc1, nb16, N,
                                                   ei, bktCnt, E, nbkt, gblocks, cb);
    } else {
        k_encB<<<gblocks, 256, 0, stream>>>(x, Wn, bn, wpk, b1, nbuf, acc1, N);
        if (fastSort)
            k_phase1<<<CNTB, 256, 0, stream>>>(x, Wn, bn, wpk, b1, acc1, nb16, N,
                                               ei, bktCnt, E, nbkt, 0, CNTB);
    }

    // ---- edge sort ----
    if (fastSort) {
        int2* tmp = (int2*)Sepool;                    // Sepool free until agg1
        k_partA<<<(E + PA_CH - 1)/PA_CH, 256, 0, stream>>>(ei, ea, et, bktCnt,
                                                           cursorRel, tmp, E, nbkt);
        k_partB2<<<nbkt, 256, 0, stream>>>(tmp, bktCnt, off8, srec, K8, nbkt);
    } else {
        k_histd<<<(E + 255)/256, 256, 0, stream>>>(ei, et, deg8, E);
        k_bsum<<<nb, 256, 0, stream>>>(deg8, bsum, K8);
        k_bscan<<<1, 256, 0, stream>>>(bsum, nb);
        k_bapply<<<nb, 256, 0, stream>>>(deg8, bsum, off8, cursor, K8);
        k_scatd<<<(E + 255)/256, 256, 0, stream>>>(ei, ea, et, cursor, srec, E);
    }

    int aggBlocks = 4096;
    if (G == 8) {
        // layer 1: aggregate-then-transform (gather from 12.8MB bf16 n-table)
        k_agg1n<<<aggBlocks, 256, 0, stream>>>(srec, off8, nb16, We, be,
                                               Vbf, Sepool, N);
        k_gemm1<<<gblocks, 256, 0, stream>>>(Vbf, Sepool, wpk, acc1, N);
        k_hrowV<<<gblocks, 256, 0, stream>>>(acc1, acc2, wpk, b2, Vbf, planeElems, N);
        k_agg2f<<<aggBlocks, 256, 0, stream>>>(srec, off8, Vbf, planeElems, acc2, N);
    } else {
        int Gc1 = G;
        k_vgemmB<<<gblocks, 256, 0, stream>>>(nbuf, wpk, 0, 0, Gc1, Vbf, planeElems, N);
        k_agg1e<<<aggBlocks, 256, 0, stream>>>(srec, off8, Vbf, planeElems, We, be,
                                               acc1, Sepool, N, Gc1);
        for (int g0 = Gc1; g0 < 8; g0 += G) {
            int Gc = (8 - g0 < G) ? (8 - g0) : G;
            k_vgemmB<<<gblocks, 256, 0, stream>>>(nbuf, wpk, 0, g0, Gc, Vbf, planeElems, N);
            k_agg1v<<<aggBlocks, 256, 0, stream>>>(srec, off8, Vbf, planeElems,
                                                   acc1, N, g0, g0 + Gc);
        }
        k_segemm<<<gblocks, 256, 0, stream>>>(Sepool, wpk, acc1, N);
        k_hrowB<<<gblocks, 256, 0, stream>>>(acc1, acc2, wpk, b2, N);
        for (int g0 = 0; g0 < 8; g0 += G) {
            int Gc = (8 - g0 < G) ? (8 - g0) : G;
            k_vgemmB<<<gblocks, 256, 0, stream>>>(acc1, wpk, 16, g0, Gc, Vbf, planeElems, N);
            k_agg2<<<aggBlocks, 256, 0, stream>>>(srec, off8, Vbf, planeElems,
                                                  acc2, N, g0, g0 + Gc);
        }
    }
    k_finB<<<gblocks, 256, 0, stream>>>(acc2, omega, Wo, bo, wpk, bagg, Wc, bc, out, N);
}

// Round 10
// 451.292 us; speedup vs baseline: 1.1346x; 1.1346x over previous
//
#include <hip/hip_runtime.h>
#include <cmath>

typedef __attribute__((ext_vector_type(8))) short short8;
typedef __attribute__((ext_vector_type(4))) float floatx4;

// ---------- helpers ----------
__device__ __forceinline__ unsigned short rnbf(float f) {
    unsigned u = __float_as_uint(f);
    u += 0x7fffu + ((u >> 16) & 1u);
    return (unsigned short)(u >> 16);
}
__device__ __forceinline__ float bf2f(unsigned short h) {
    return __uint_as_float(((unsigned)h) << 16);
}
__device__ __forceinline__ int rfl(int v) { return __builtin_amdgcn_readfirstlane(v); }
__device__ __forceinline__ float eAct(unsigned ry, float we0, float we1, float bev) {
    float a0 = __uint_as_float(ry & 0xFFFF0000u);
    float a1 = __uint_as_float(ry << 16);
    return fmaxf(fmaf(a1, we1, fmaf(a0, we0, bev)), 0.f);
}
__device__ __forceinline__ unsigned vidx(int x, unsigned pl, int lane) {
    return (((unsigned)x >> 24) & 7u)*pl + (unsigned)(x & 0xFFFFFF)*64u + (unsigned)lane;
}
__device__ __forceinline__ void mstep(int r, float v, int& cur, float& mx, float& add) {
    bool nb = (r != cur);
    add += nb ? mx : 0.f;
    mx = nb ? v : fmaxf(mx, v);
    cur = r;
}

// ================= fallback sort pipeline (N > 2^17) =================
__global__ void k_histd(const int* __restrict__ ei, const int* __restrict__ et,
                        int* __restrict__ deg8, int E)
{
    int e = blockIdx.x*blockDim.x + threadIdx.x;
    if (e < E) atomicAdd(&deg8[ei[E + e]*8 + et[e]], 1);
}
#define SCHUNK 1024
__global__ void k_bsum(const int* __restrict__ deg, int* __restrict__ bsum, int K)
{
    __shared__ int s[256];
    int b = blockIdx.x, t = threadIdx.x;
    int base = b*SCHUNK;
    int v = 0;
    for (int k = t; k < SCHUNK; k += 256) { int i = base + k; v += (i < K) ? deg[i] : 0; }
    s[t] = v; __syncthreads();
    for (int o = 128; o; o >>= 1) { if (t < o) s[t] += s[t+o]; __syncthreads(); }
    if (t == 0) bsum[b] = s[0];
}
__global__ void k_bscan(int* __restrict__ bsum, int nb)
{
    __shared__ int ts[256];
    int t = threadIdx.x;
    int v[4]; int loc = 0;
    #pragma unroll
    for (int u = 0; u < 4; ++u) { int i = t*4+u; v[u] = (i < nb) ? bsum[i] : 0; loc += v[u]; }
    ts[t] = loc; __syncthreads();
    for (int o = 1; o < 256; o <<= 1) {
        int add = (t >= o) ? ts[t-o] : 0;
        __syncthreads();
        ts[t] += add;
        __syncthreads();
    }
    int excl = ts[t] - loc;
    #pragma unroll
    for (int u = 0; u < 4; ++u) {
        int i = t*4+u;
        if (i < nb) bsum[i] = excl;
        excl += v[u];
    }
}
__global__ void k_bapply(const int* __restrict__ deg, const int* __restrict__ bsum,
                         int* __restrict__ off, int* __restrict__ cursor, int K)
{
    __shared__ int ts[256];
    int b = blockIdx.x, t = threadIdx.x;
    int base = b*SCHUNK;
    int v[4]; int loc = 0;
    #pragma unroll
    for (int u = 0; u < 4; ++u) { int i = base + t*4 + u; v[u] = (i < K) ? deg[i] : 0; loc += v[u]; }
    ts[t] = loc; __syncthreads();
    for (int o = 1; o < 256; o <<= 1) {
        int add = (t >= o) ? ts[t-o] : 0;
        __syncthreads();
        ts[t] += add;
        __syncthreads();
    }
    int excl = ts[t] - loc + bsum[b];
    #pragma unroll
    for (int u = 0; u < 4; ++u) {
        int i = base + t*4 + u;
        if (i < K) { off[i] = excl; cursor[i] = excl; }
        excl += v[u];
        if (i == K-1) off[K] = excl;
    }
}
__global__ void k_scatd(const int* __restrict__ ei, const float* __restrict__ ea,
                        const int* __restrict__ et, int* __restrict__ cursor,
                        int2* __restrict__ srec, int E)
{
    int e = blockIdx.x*blockDim.x + threadIdx.x;
    if (e >= E) return;
    int rel = et[e];
    int key = ei[E + e]*8 + rel;
    int pos = atomicAdd(&cursor[key], 1);
    float2 a = ((const float2*)ea)[e];
    int xv = ei[e] | (rel << 24);
    int yv = ((int)rnbf(a.x) << 16) | (int)rnbf(a.y);
    srec[pos] = make_int2(xv, yv);
}

// ================= fast sort: bucket partition, self-contained =================
// bucket = dst>>9 (512 nodes, PB_KEYS=4096 (dst,rel)-keys per bucket)
#define PB_KEYS 4096
#define PA_CH   4096
#define CNTB    512

// ---------- device body: bucket count (grid-stride over E) ----------
__device__ __forceinline__ void dev_cnt(const int* __restrict__ ei,
                                        int* __restrict__ bktCnt,
                                        int E, int nbkt, int cb, int cgrid)
{
    __shared__ int cnt[512];
    for (int j = threadIdx.x; j < nbkt; j += 256) cnt[j] = 0;
    __syncthreads();
    int stride = cgrid*256;
    for (int e = cb*256 + threadIdx.x; e < E; e += stride)
        atomicAdd(&cnt[ei[E + e] >> 9], 1);
    __syncthreads();
    for (int j = threadIdx.x; j < nbkt; j += 256) {
        int c = cnt[j];
        if (c) atomicAdd(&bktCnt[j], c);
    }
}

// ---------- device body: encoder + root1 + 8 layer-1 V planes ----------
__device__ __forceinline__ void dev_encV(
    const float* __restrict__ x,
    const float* __restrict__ Wn, const float* __restrict__ bn,
    const unsigned short* __restrict__ wpk, const float* __restrict__ b1,
    float* __restrict__ acc1, unsigned short* __restrict__ Vbf,
    size_t plane, int N, int bid)
{
    int lane = threadIdx.x & 63;
    int wave = threadIdx.x >> 6;
    int n0 = bid*64 + 16*wave;
    int m = lane & 15, q = lane >> 4;
    int node = n0 + m; if (node >= N) node = N - 1;
    float x0 = x[3*node], x1 = x[3*node+1], x2 = x[3*node+2];
    short8 ah[2], al[2];
    #pragma unroll
    for (int ks = 0; ks < 2; ++ks) {
        #pragma unroll
        for (int i = 0; i < 8; ++i) {
            int f = ks*32 + q*8 + i;
            float nf = fmaxf(fmaf(x2, Wn[128+f], fmaf(x1, Wn[64+f], fmaf(x0, Wn[f], bn[f]))), 0.f);
            unsigned short hb = rnbf(nf);
            ah[ks][i] = (short)hb;
            al[ks][i] = (short)rnbf(nf - bf2f(hb));
        }
    }
    // root1 -> acc1
    {
        floatx4 acc[4];
        #pragma unroll
        for (int jt = 0; jt < 4; ++jt) acc[jt] = (floatx4){0.f,0.f,0.f,0.f};
        #pragma unroll
        for (int ks = 0; ks < 2; ++ks) {
            int unit = 40 + ks;
            #pragma unroll
            for (int jt = 0; jt < 4; ++jt) {
                const unsigned short* qp = wpk + (((size_t)unit*4 + jt)*64 + lane)*16;
                short8 bh = *(const short8*)qp;
                short8 bl = *(const short8*)(qp + 8);
                acc[jt] = __builtin_amdgcn_mfma_f32_16x16x32_bf16(ah[ks], bh, acc[jt], 0,0,0);
                acc[jt] = __builtin_amdgcn_mfma_f32_16x16x32_bf16(ah[ks], bl, acc[jt], 0,0,0);
                acc[jt] = __builtin_amdgcn_mfma_f32_16x16x32_bf16(al[ks], bh, acc[jt], 0,0,0);
            }
        }
        #pragma unroll
        for (int jt = 0; jt < 4; ++jt) {
            float bb = b1[jt*16 + m];
            #pragma unroll
            for (int t = 0; t < 4; ++t) {
                int row = n0 + q*4 + t;
                if (row < N) acc1[(size_t)row*64 + jt*16 + m] = acc[jt][t] + bb;
            }
        }
    }
    // 8 V planes
    for (int p = 0; p < 8; ++p) {
        floatx4 acc[4];
        #pragma unroll
        for (int jt = 0; jt < 4; ++jt) acc[jt] = (floatx4){0.f,0.f,0.f,0.f};
        #pragma unroll
        for (int ks = 0; ks < 2; ++ks) {
            int unit = p*2 + ks;
            #pragma unroll
            for (int jt = 0; jt < 4; ++jt) {
                const unsigned short* qp = wpk + (((size_t)unit*4 + jt)*64 + lane)*16;
                short8 bh = *(const short8*)qp;
                short8 bl = *(const short8*)(qp + 8);
                acc[jt] = __builtin_amdgcn_mfma_f32_16x16x32_bf16(ah[ks], bh, acc[jt], 0,0,0);
                acc[jt] = __builtin_amdgcn_mfma_f32_16x16x32_bf16(ah[ks], bl, acc[jt], 0,0,0);
                acc[jt] = __builtin_amdgcn_mfma_f32_16x16x32_bf16(al[ks], bh, acc[jt], 0,0,0);
            }
        }
        unsigned short* Vp = Vbf + (size_t)p*plane;
        #pragma unroll
        for (int jt = 0; jt < 4; ++jt) {
            #pragma unroll
            for (int t = 0; t < 4; ++t) {
                int row = n0 + q*4 + t;
                if (row < N) Vp[(size_t)row*64 + jt*16 + m] = rnbf(acc[jt][t]);
            }
        }
    }
}

// ---------- phase-1 mega-kernel: encV blocks || bucket-count blocks ----------
__global__ __launch_bounds__(256) void k_phase1(
    const float* __restrict__ x,
    const float* __restrict__ Wn, const float* __restrict__ bn,
    const unsigned short* __restrict__ wpk, const float* __restrict__ b1,
    float* __restrict__ acc1, unsigned short* __restrict__ Vbf,
    size_t plane, int N,
    const int* __restrict__ ei, int* __restrict__ bktCnt, int E, int nbkt,
    int encBlocks, int cntBlocks)
{
    int bid = (int)blockIdx.x;
    if (bid < encBlocks) {
        dev_encV(x, Wn, bn, wpk, b1, acc1, Vbf, plane, N, bid);
    } else {
        dev_cnt(ei, bktCnt, E, nbkt, bid - encBlocks, cntBlocks);
    }
}

// pass A: local scan of bktCnt gives bucket bases; reserve runs via cursorRel.
// tmp rec: x = src(17b) | rel<<17 | (dst&511)<<20 ; y = packed bf16 attrs
__global__ __launch_bounds__(256) void k_partA(
    const int* __restrict__ ei, const float* __restrict__ ea,
    const int* __restrict__ et, const int* __restrict__ bktCnt,
    int* __restrict__ cursorRel, int2* __restrict__ tmp, int E, int nbkt)
{
    __shared__ int cnt[512], base[512], gbase[256];
    __shared__ int ts[256];
    int t = threadIdx.x;
    // local exclusive scan of bucket counts -> global bucket bases
    {
        int v = (t < nbkt) ? bktCnt[t] : 0;
        ts[t] = v; __syncthreads();
        for (int o = 1; o < 256; o <<= 1) {
            int add = (t >= o) ? ts[t-o] : 0;
            __syncthreads();
            ts[t] += add;
            __syncthreads();
        }
        gbase[t] = ts[t] - v;
    }
    int b0 = blockIdx.x * PA_CH;
    for (int j = t; j < nbkt; j += 256) cnt[j] = 0;
    __syncthreads();
    int2 rec[16]; int bk[16];
    #pragma unroll
    for (int u = 0; u < 16; ++u) {
        int e = b0 + u*256 + t;
        bk[u] = -1;
        if (e < E) {
            int rel = et[e];
            int src = ei[e];
            int dst = ei[E + e];
            float2 a = ((const float2*)ea)[e];
            rec[u] = make_int2(src | (rel << 17) | ((dst & 511) << 20),
                               ((int)rnbf(a.x) << 16) | (int)rnbf(a.y));
            bk[u] = dst >> 9;
            atomicAdd(&cnt[bk[u]], 1);
        }
    }
    __syncthreads();
    for (int j = t; j < nbkt; j += 256) {
        int c = cnt[j];
        base[j] = c ? (gbase[j] + atomicAdd(&cursorRel[j], c)) : 0;
    }
    __syncthreads();
    for (int j = t; j < nbkt; j += 256) cnt[j] = 0;
    __syncthreads();
    #pragma unroll
    for (int u = 0; u < 16; ++u) {
        if (bk[u] >= 0) {
            int pos = base[bk[u]] + atomicAdd(&cnt[bk[u]], 1);
            tmp[pos] = rec[u];
        }
    }
}
// pass B2: one block per bucket; local bucket-scan for range, local key-hist +
// scan produces off8 (coalesced) and exact placement.
__global__ __launch_bounds__(256) void k_partB2(
    const int2* __restrict__ tmp, const int* __restrict__ bktCnt,
    int* __restrict__ off8, int2* __restrict__ srec, int K8, int nbkt)
{
    __shared__ int cnt[PB_KEYS];
    __shared__ int ts[256];
    __shared__ int sb[2];
    int b = blockIdx.x;
    int t = threadIdx.x;
    // local exclusive scan of bucket counts -> this bucket's [bstart, bend)
    {
        int v = (t < nbkt) ? bktCnt[t] : 0;
        ts[t] = v; __syncthreads();
        for (int o = 1; o < 256; o <<= 1) {
            int add = (t >= o) ? ts[t-o] : 0;
            __syncthreads();
            ts[t] += add;
            __syncthreads();
        }
        if (t == b) { sb[0] = ts[t] - v; sb[1] = ts[t]; }
    }
    __syncthreads();
    int bstart = sb[0];
    int bend = sb[1];
    int kbase = b * PB_KEYS;
    int kend = kbase + PB_KEYS; if (kend > K8) kend = K8;
    int nk = kend - kbase;
    for (int j = t; j < PB_KEYS; j += 256) cnt[j] = 0;
    __syncthreads();
    // pass 1: histogram keys
    for (int i = bstart + t; i < bend; i += 256) {
        unsigned xw = (unsigned)tmp[i].x;
        int key = (int)((xw >> 20) & 511u)*8 + (int)((xw >> 17) & 7u);
        atomicAdd(&cnt[key], 1);
    }
    __syncthreads();
    // exclusive scan of cnt[0..4095], thread owns 16 consecutive keys
    int loc[16]; int lsum = 0;
    #pragma unroll
    for (int u = 0; u < 16; ++u) { loc[u] = cnt[t*16 + u]; lsum += loc[u]; }
    ts[t] = lsum; __syncthreads();
    for (int o = 1; o < 256; o <<= 1) {
        int add = (t >= o) ? ts[t-o] : 0;
        __syncthreads();
        ts[t] += add;
        __syncthreads();
    }
    int excl = ts[t] - lsum + bstart;
    #pragma unroll
    for (int u = 0; u < 16; ++u) {
        int j = t*16 + u;
        cnt[j] = excl;                                // cursor
        if (j < nk) off8[kbase + j] = excl;           // coalesced off8 write
        excl += loc[u];
    }
    if (t == 0 && kend == K8) off8[K8] = bend;
    __syncthreads();
    // pass 2: exact placement (writes land in bucket's contiguous range)
    for (int i = bstart + t; i < bend; i += 256) {
        int2 r = tmp[i];
        unsigned xw = (unsigned)r.x;
        int src = (int)(xw & 0x1FFFFu);
        int rel = (int)((xw >> 17) & 7u);
        int key = (int)((xw >> 20) & 511u)*8 + rel;
        int pos = atomicAdd(&cnt[key], 1);
        srec[pos] = make_int2(src | (rel << 24), r.y);
    }
}

// ---------- pack weights into MFMA B-fragment order, split bf16 hi/lo ----------
// units: [0,16)=W1A rel=u>>1,ks=u&1 rows0..63; [16,32)=W2; [32,40)=W1B rows64..95;
//        [40,42)=Wroot1; [42,44)=Wroot2; [44,48)=Wagg (K=128)
__global__ __launch_bounds__(64) void k_wpack(
    const float* __restrict__ W1, const float* __restrict__ W2,
    const float* __restrict__ Wroot1, const float* __restrict__ Wroot2,
    const float* __restrict__ Wagg, unsigned short* __restrict__ wpk)
{
    int unit = blockIdx.x >> 2;
    int jt = blockIdx.x & 3;
    int lane = threadIdx.x;
    const float* Wb;
    int kbase;
    if (unit < 16) {
        Wb = W1 + (size_t)(unit >> 1)*96*64;
        kbase = (unit & 1)*32;
    } else if (unit < 32) {
        Wb = W2 + (size_t)((unit - 16) >> 1)*64*64;
        kbase = ((unit - 16) & 1)*32;
    } else if (unit < 40) {
        Wb = W1 + (size_t)(unit - 32)*96*64;
        kbase = 64;
    } else if (unit < 42) {
        Wb = Wroot1; kbase = (unit - 40)*32;
    } else if (unit < 44) {
        Wb = Wroot2; kbase = (unit - 42)*32;
    } else {
        Wb = Wagg;   kbase = (unit - 44)*32;
    }
    int j = jt*16 + (lane & 15);
    size_t base = (((size_t)unit*4 + jt)*64 + lane)*16;
    #pragma unroll
    for (int i = 0; i < 8; ++i) {
        int k = kbase + (lane >> 4)*8 + i;
        float f = Wb[(size_t)k*64 + j];
        unsigned short hi = rnbf(f);
        unsigned short lo = rnbf(f - bf2f(hi));
        wpk[base + i] = hi;
        wpk[base + 8 + i] = lo;
    }
}

// ---------- fallback: encoder (writes nbuf) ----------
__global__ __launch_bounds__(256) void k_encB(
    const float* __restrict__ x,
    const float* __restrict__ Wn, const float* __restrict__ bn,
    const unsigned short* __restrict__ wpk, const float* __restrict__ b1,
    float* __restrict__ nbuf, float* __restrict__ acc1, int N)
{
    int lane = threadIdx.x & 63;
    int wave = threadIdx.x >> 6;
    int n0 = blockIdx.x*64 + 16*wave;
    int m = lane & 15, q = lane >> 4;
    #pragma unroll 4
    for (int t = 0; t < 16; ++t) {
        int nd = n0 + t;
        if (nd < N) {
            float x0 = x[3*nd], x1 = x[3*nd+1], x2 = x[3*nd+2];
            float nj = fmaxf(fmaf(x2, Wn[128+lane], fmaf(x1, Wn[64+lane], fmaf(x0, Wn[lane], bn[lane]))), 0.f);
            nbuf[(size_t)nd*64 + lane] = nj;
        }
    }
    int node = n0 + m; if (node >= N) node = N - 1;
    float x0 = x[3*node], x1 = x[3*node+1], x2 = x[3*node+2];
    short8 ah[2], al[2];
    #pragma unroll
    for (int ks = 0; ks < 2; ++ks) {
        #pragma unroll
        for (int i = 0; i < 8; ++i) {
            int f = ks*32 + q*8 + i;
            float nf = fmaxf(fmaf(x2, Wn[128+f], fmaf(x1, Wn[64+f], fmaf(x0, Wn[f], bn[f]))), 0.f);
            unsigned short hb = rnbf(nf);
            ah[ks][i] = (short)hb;
            al[ks][i] = (short)rnbf(nf - bf2f(hb));
        }
    }
    floatx4 acc[4];
    #pragma unroll
    for (int jt = 0; jt < 4; ++jt) acc[jt] = (floatx4){0.f,0.f,0.f,0.f};
    #pragma unroll
    for (int ks = 0; ks < 2; ++ks) {
        int unit = 40 + ks;
        #pragma unroll
        for (int jt = 0; jt < 4; ++jt) {
            const unsigned short* qp = wpk + (((size_t)unit*4 + jt)*64 + lane)*16;
            short8 bh = *(const short8*)qp;
            short8 bl = *(const short8*)(qp + 8);
            acc[jt] = __builtin_amdgcn_mfma_f32_16x16x32_bf16(ah[ks], bh, acc[jt], 0,0,0);
            acc[jt] = __builtin_amdgcn_mfma_f32_16x16x32_bf16(ah[ks], bl, acc[jt], 0,0,0);
            acc[jt] = __builtin_amdgcn_mfma_f32_16x16x32_bf16(al[ks], bh, acc[jt], 0,0,0);
        }
    }
    #pragma unroll
    for (int jt = 0; jt < 4; ++jt) {
        float bb = b1[jt*16 + m];
        #pragma unroll
        for (int t = 0; t < 4; ++t) {
            int row = n0 + q*4 + t;
            if (row < N) acc1[(size_t)row*64 + jt*16 + m] = acc[jt][t] + bb;
        }
    }
}

// ---------- fallback dense GEMM via MFMA split-bf16, bf16 output ----------
__global__ __launch_bounds__(256) void k_vgemmB(
    const float* __restrict__ F, const unsigned short* __restrict__ wpk,
    int unitBase, int g0, int Gc, unsigned short* __restrict__ Vbf,
    size_t plane, int N)
{
    int lane = threadIdx.x & 63;
    int wave = threadIdx.x >> 6;
    int n0 = blockIdx.x*64 + 16*wave;
    int m = lane & 15, q = lane >> 4;
    int node = n0 + m;
    if (node >= N) node = N - 1;
    const float4* Fr = (const float4*)(F + (size_t)node*64);
    short8 ah[2], al[2];
    #pragma unroll
    for (int ks = 0; ks < 2; ++ks) {
        float4 u0 = Fr[ks*8 + q*2];
        float4 u1 = Fr[ks*8 + q*2 + 1];
        float fv[8] = {u0.x,u0.y,u0.z,u0.w,u1.x,u1.y,u1.z,u1.w};
        #pragma unroll
        for (int i = 0; i < 8; ++i) {
            unsigned short hb = rnbf(fv[i]);
            ah[ks][i] = (short)hb;
            al[ks][i] = (short)rnbf(fv[i] - bf2f(hb));
        }
    }
    for (int p = 0; p < Gc; ++p) {
        int rel = g0 + p;
        floatx4 acc[4];
        #pragma unroll
        for (int jt = 0; jt < 4; ++jt) acc[jt] = (floatx4){0.f,0.f,0.f,0.f};
        #pragma unroll
        for (int ks = 0; ks < 2; ++ks) {
            int unit = unitBase + rel*2 + ks;
            #pragma unroll
            for (int jt = 0; jt < 4; ++jt) {
                const unsigned short* qp = wpk + (((size_t)unit*4 + jt)*64 + lane)*16;
                short8 bh = *(const short8*)qp;
                short8 bl = *(const short8*)(qp + 8);
                acc[jt] = __builtin_amdgcn_mfma_f32_16x16x32_bf16(ah[ks], bh, acc[jt], 0,0,0);
                acc[jt] = __builtin_amdgcn_mfma_f32_16x16x32_bf16(ah[ks], bl, acc[jt], 0,0,0);
                acc[jt] = __builtin_amdgcn_mfma_f32_16x16x32_bf16(al[ks], bh, acc[jt], 0,0,0);
            }
        }
        unsigned short* Vp = Vbf + (size_t)p*plane;
        #pragma unroll
        for (int jt = 0; jt < 4; ++jt) {
            #pragma unroll
            for (int t = 0; t < 4; ++t) {
                int row = n0 + q*4 + t;
                if (row < N) Vp[(size_t)row*64 + jt*16 + m] = rnbf(acc[jt][t]);
            }
        }
    }
}

// ---------- layer-1 pass 1 (G==8 fast path): FLAT node-edge walk, 16-deep ----------
__global__ __launch_bounds__(256) void k_agg1ef(
    const int2* __restrict__ srec, const int* __restrict__ off8,
    const unsigned short* __restrict__ Vbf, size_t plane,
    const float* __restrict__ We, const float* __restrict__ be,
    float* __restrict__ acc1, unsigned short* __restrict__ Sep, int N)
{
    int lane = threadIdx.x & 63;
    int wv = threadIdx.x >> 6;
    unsigned pl = (unsigned)plane;
    float we0 = We[lane & 31], we1 = We[32 + (lane & 31)], bev = be[lane & 31];
    int stride = gridDim.x*4;
    for (int node = blockIdx.x*4 + wv; node < N; node += stride) {
        const int* ofp = off8 + node*8;
        int o0 = rfl(ofp[0]), o8 = rfl(ofp[8]);
        float vsum = 0.f;
        int i = o0;
        for (; i + 16 <= o8; i += 16) {
            int2 q[16];
            #pragma unroll
            for (int u = 0; u < 16; ++u) q[u] = srec[i+u];
            int xs[16];
            #pragma unroll
            for (int u = 0; u < 16; ++u) xs[u] = rfl(q[u].x);
            float v[16];
            #pragma unroll
            for (int u = 0; u < 16; ++u) v[u] = bf2f(Vbf[vidx(xs[u], pl, lane)]);
            float s01 = (v[0]+v[1]) + (v[2]+v[3]);
            float s23 = (v[4]+v[5]) + (v[6]+v[7]);
            float s45 = (v[8]+v[9]) + (v[10]+v[11]);
            float s67 = (v[12]+v[13]) + (v[14]+v[15]);
            vsum += (s01 + s23) + (s45 + s67);
        }
        for (; i + 8 <= o8; i += 8) {
            int2 q0 = srec[i+0], q1 = srec[i+1], q2 = srec[i+2], q3 = srec[i+3];
            int2 q4 = srec[i+4], q5 = srec[i+5], q6 = srec[i+6], q7 = srec[i+7];
            int x0 = rfl(q0.x), x1 = rfl(q1.x), x2 = rfl(q2.x), x3 = rfl(q3.x);
            int x4 = rfl(q4.x), x5 = rfl(q5.x), x6 = rfl(q6.x), x7 = rfl(q7.x);
            float v0 = bf2f(Vbf[vidx(x0, pl, lane)]);
            float v1 = bf2f(Vbf[vidx(x1, pl, lane)]);
            float v2 = bf2f(Vbf[vidx(x2, pl, lane)]);
            float v3 = bf2f(Vbf[vidx(x3, pl, lane)]);
            float v4 = bf2f(Vbf[vidx(x4, pl, lane)]);
            float v5 = bf2f(Vbf[vidx(x5, pl, lane)]);
            float v6 = bf2f(Vbf[vidx(x6, pl, lane)]);
            float v7 = bf2f(Vbf[vidx(x7, pl, lane)]);
            vsum += ((v0+v1)+(v2+v3)) + ((v4+v5)+(v6+v7));
        }
        for (; i < o8; ++i) {
            int xx = rfl(srec[i].x);
            vsum += bf2f(Vbf[vidx(xx, pl, lane)]);
        }
        int o1 = rfl(ofp[1]), o2 = rfl(ofp[2]), o3 = rfl(ofp[3]), o4 = rfl(ofp[4]);
        int o5 = rfl(ofp[5]), o6 = rfl(ofp[6]), o7 = rfl(ofp[7]);
        const unsigned* sy = (const unsigned*)srec;
        float se0=0,se1=0,se2=0,se3=0,se4=0,se5=0,se6=0,se7=0;
        #pragma unroll
        for (int r = 0; r < 8; ++r) {
            int s = (r==0)?o0:(r==1)?o1:(r==2)?o2:(r==3)?o3:(r==4)?o4:(r==5)?o5:(r==6)?o6:o7;
            int e = (r==0)?o1:(r==1)?o2:(r==2)?o3:(r==3)?o4:(r==4)?o5:(r==5)?o6:(r==6)?o7:o8;
            if (s == e) continue;
            float ev = 0.f;
            int k = s;
            for (; k + 4 <= e; k += 4) {
                unsigned y0 = sy[2*(k+0)+1], y1 = sy[2*(k+1)+1];
                unsigned y2 = sy[2*(k+2)+1], y3 = sy[2*(k+3)+1];
                ev += eAct(y0, we0, we1, bev);
                ev += eAct(y1, we0, we1, bev);
                ev += eAct(y2, we0, we1, bev);
                ev += eAct(y3, we0, we1, bev);
            }
            for (; k < e; ++k) ev += eAct(sy[2*k+1], we0, we1, bev);
            if (r == 0) se0 = ev;  if (r == 1) se1 = ev;
            if (r == 2) se2 = ev;  if (r == 3) se3 = ev;
            if (r == 4) se4 = ev;  if (r == 5) se5 = ev;
            if (r == 6) se6 = ev;  if (r == 7) se7 = ev;
        }
        unsigned short* Sp = Sep + (size_t)node*256;
        Sp[0*64 + lane] = rnbf((lane < 32) ? se0 : se1);
        Sp[1*64 + lane] = rnbf((lane < 32) ? se2 : se3);
        Sp[2*64 + lane] = rnbf((lane < 32) ? se4 : se5);
        Sp[3*64 + lane] = rnbf((lane < 32) ? se6 : se7);
        if (o0 != o8) acc1[(size_t)node*64 + lane] += vsum;
    }
}

// ---------- layer-1 pass 1 (fallback G<8) ----------
__global__ __launch_bounds__(256) void k_agg1e(
    const int2* __restrict__ srec, const int* __restrict__ off8,
    const unsigned short* __restrict__ Vbf, size_t plane,
    const float* __restrict__ We, const float* __restrict__ be,
    float* __restrict__ acc1, unsigned short* __restrict__ Sep, int N, int Gc)
{
    int lane = threadIdx.x & 63;
    int wv = threadIdx.x >> 6;
    float we0 = We[lane & 31], we1 = We[32 + (lane & 31)], bev = be[lane & 31];
    int stride = gridDim.x*4;
    for (int node = blockIdx.x*4 + wv; node < N; node += stride) {
        int o0 = rfl(off8[node*8+0]), o1 = rfl(off8[node*8+1]), o2 = rfl(off8[node*8+2]);
        int o3 = rfl(off8[node*8+3]), o4 = rfl(off8[node*8+4]), o5 = rfl(off8[node*8+5]);
        int o6 = rfl(off8[node*8+6]), o7 = rfl(off8[node*8+7]), o8 = rfl(off8[node*8+8]);
        float vsum = 0.f;
        float se0=0,se1=0,se2=0,se3=0,se4=0,se5=0,se6=0,se7=0;
        #pragma unroll
        for (int r = 0; r < 8; ++r) {
            int s = (r==0)?o0:(r==1)?o1:(r==2)?o2:(r==3)?o3:(r==4)?o4:(r==5)?o5:(r==6)?o6:o7;
            int e = (r==0)?o1:(r==1)?o2:(r==2)?o3:(r==3)?o4:(r==4)?o5:(r==5)?o6:(r==6)?o7:o8;
            if (s == e) continue;
            const unsigned short* Vp = Vbf + (size_t)r*plane;
            bool doV = (r < Gc);
            float ev = 0.f;
            int i = s;
            for (; i + 8 <= e; i += 8) {
                int2 q0 = srec[i+0], q1 = srec[i+1], q2 = srec[i+2], q3 = srec[i+3];
                int2 q4 = srec[i+4], q5 = srec[i+5], q6 = srec[i+6], q7 = srec[i+7];
                if (doV) {
                    float v0 = bf2f(Vp[(size_t)(rfl(q0.x) & 0xFFFFFF)*64 + lane]);
                    float v1 = bf2f(Vp[(size_t)(rfl(q1.x) & 0xFFFFFF)*64 + lane]);
                    float v2 = bf2f(Vp[(size_t)(rfl(q2.x) & 0xFFFFFF)*64 + lane]);
                    float v3 = bf2f(Vp[(size_t)(rfl(q3.x) & 0xFFFFFF)*64 + lane]);
                    float v4 = bf2f(Vp[(size_t)(rfl(q4.x) & 0xFFFFFF)*64 + lane]);
                    float v5 = bf2f(Vp[(size_t)(rfl(q5.x) & 0xFFFFFF)*64 + lane]);
                    float v6 = bf2f(Vp[(size_t)(rfl(q6.x) & 0xFFFFFF)*64 + lane]);
                    float v7 = bf2f(Vp[(size_t)(rfl(q7.x) & 0xFFFFFF)*64 + lane]);
                    vsum += ((v0+v1)+(v2+v3)) + ((v4+v5)+(v6+v7));
                }
                ev += eAct((unsigned)q0.y, we0, we1, bev);
                ev += eAct((unsigned)q1.y, we0, we1, bev);
                ev += eAct((unsigned)q2.y, we0, we1, bev);
                ev += eAct((unsigned)q3.y, we0, we1, bev);
                ev += eAct((unsigned)q4.y, we0, we1, bev);
                ev += eAct((unsigned)q5.y, we0, we1, bev);
                ev += eAct((unsigned)q6.y, we0, we1, bev);
                ev += eAct((unsigned)q7.y, we0, we1, bev);
            }
            for (; i < e; ++i) {
                int2 qq = srec[i];
                if (doV) vsum += bf2f(Vp[(size_t)(rfl(qq.x) & 0xFFFFFF)*64 + lane]);
                ev += eAct((unsigned)qq.y, we0, we1, bev);
            }
            if (r == 0) se0 = ev;  if (r == 1) se1 = ev;
            if (r == 2) se2 = ev;  if (r == 3) se3 = ev;
            if (r == 4) se4 = ev;  if (r == 5) se5 = ev;
            if (r == 6) se6 = ev;  if (r == 7) se7 = ev;
        }
        unsigned short* Sp = Sep + (size_t)node*256;
        Sp[0*64 + lane] = rnbf((lane < 32) ? se0 : se1);
        Sp[1*64 + lane] = rnbf((lane < 32) ? se2 : se3);
        Sp[2*64 + lane] = rnbf((lane < 32) ? se4 : se5);
        Sp[3*64 + lane] = rnbf((lane < 32) ? se6 : se7);
        if (o0 != o8) acc1[(size_t)node*64 + lane] += vsum;
    }
}

// ---------- layer-1 pass 2+ (fallback G<8) ----------
__global__ __launch_bounds__(256) void k_agg1v(
    const int2* __restrict__ srec, const int* __restrict__ off8,
    const unsigned short* __restrict__ Vbf, size_t plane,
    float* __restrict__ acc1, int N, int g0, int g1)
{
    int lane = threadIdx.x & 63;
    int wv = threadIdx.x >> 6;
    int stride = gridDim.x*4;
    for (int node = blockIdx.x*4 + wv; node < N; node += stride) {
        float vsum = 0.f;
        bool any = false;
        for (int r = g0; r < g1; ++r) {
            int s = rfl(off8[node*8 + r]);
            int e = rfl(off8[node*8 + r + 1]);
            if (s == e) continue;
            any = true;
            const unsigned short* Vp = Vbf + (size_t)(r - g0)*plane;
            int i = s;
            for (; i + 8 <= e; i += 8) {
                int s0 = rfl(srec[i+0].x) & 0xFFFFFF, s1 = rfl(srec[i+1].x) & 0xFFFFFF;
                int s2 = rfl(srec[i+2].x) & 0xFFFFFF, s3 = rfl(srec[i+3].x) & 0xFFFFFF;
                int s4 = rfl(srec[i+4].x) & 0xFFFFFF, s5 = rfl(srec[i+5].x) & 0xFFFFFF;
                int s6 = rfl(srec[i+6].x) & 0xFFFFFF, s7 = rfl(srec[i+7].x) & 0xFFFFFF;
                float v0 = bf2f(Vp[(size_t)s0*64 + lane]), v1 = bf2f(Vp[(size_t)s1*64 + lane]);
                float v2 = bf2f(Vp[(size_t)s2*64 + lane]), v3 = bf2f(Vp[(size_t)s3*64 + lane]);
                float v4 = bf2f(Vp[(size_t)s4*64 + lane]), v5 = bf2f(Vp[(size_t)s5*64 + lane]);
                float v6 = bf2f(Vp[(size_t)s6*64 + lane]), v7 = bf2f(Vp[(size_t)s7*64 + lane]);
                vsum += ((v0+v1)+(v2+v3)) + ((v4+v5)+(v6+v7));
            }
            for (; i < e; ++i) {
                int sx = rfl(srec[i].x) & 0xFFFFFF;
                vsum += bf2f(Vp[(size_t)sx*64 + lane]);
            }
        }
        if (any) acc1[(size_t)node*64 + lane] += vsum;
    }
}

// ---------- fallback: Se GEMM ----------
__global__ __launch_bounds__(256) void k_segemm(
    const unsigned short* __restrict__ Sep, const unsigned short* __restrict__ wpk,
    float* __restrict__ acc1, int N)
{
    int lane = threadIdx.x & 63;
    int wave = threadIdx.x >> 6;
    int n0 = blockIdx.x*64 + 16*wave;
    int m = lane & 15, q = lane >> 4;
    int node = n0 + m;
    if (node >= N) node = N - 1;
    floatx4 acc[4];
    #pragma unroll
    for (int jt = 0; jt < 4; ++jt) acc[jt] = (floatx4){0.f,0.f,0.f,0.f};
    for (int rel = 0; rel < 8; ++rel) {
        short8 ah = *(const short8*)(Sep + (size_t)node*256 + rel*32 + q*8);
        int unit = 32 + rel;
        #pragma unroll
        for (int jt = 0; jt < 4; ++jt) {
            const unsigned short* qp = wpk + (((size_t)unit*4 + jt)*64 + lane)*16;
            short8 bh = *(const short8*)qp;
            short8 bl = *(const short8*)(qp + 8);
            acc[jt] = __builtin_amdgcn_mfma_f32_16x16x32_bf16(ah, bh, acc[jt], 0,0,0);
            acc[jt] = __builtin_amdgcn_mfma_f32_16x16x32_bf16(ah, bl, acc[jt], 0,0,0);
        }
    }
    #pragma unroll
    for (int jt = 0; jt < 4; ++jt) {
        #pragma unroll
        for (int t = 0; t < 4; ++t) {
            int row = n0 + q*4 + t;
            if (row < N) acc1[(size_t)row*64 + jt*16 + m] += acc[jt][t];
        }
    }
}

// ---------- fallback: hrow ----------
__global__ __launch_bounds__(256) void k_hrowB(
    float* __restrict__ acc1, float* __restrict__ acc2,
    const unsigned short* __restrict__ wpk, const float* __restrict__ b2, int N)
{
    int lane = threadIdx.x & 63;
    int wave = threadIdx.x >> 6;
    int n0 = blockIdx.x*64 + 16*wave;
    int m = lane & 15, q = lane >> 4;
    int node = n0 + m;
    if (node >= N) node = N - 1;
    float4* Fr = (float4*)(acc1 + (size_t)node*64);
    short8 ah[2], al[2];
    #pragma unroll
    for (int ks = 0; ks < 2; ++ks) {
        float4 u0 = Fr[ks*8 + q*2];
        float4 u1 = Fr[ks*8 + q*2 + 1];
        float fv[8] = {u0.x,u0.y,u0.z,u0.w,u1.x,u1.y,u1.z,u1.w};
        #pragma unroll
        for (int i = 0; i < 8; ++i) {
            float hv = fmaxf(fv[i], 0.f);
            fv[i] = hv;
            unsigned short hb = rnbf(hv);
            ah[ks][i] = (short)hb;
            al[ks][i] = (short)rnbf(hv - bf2f(hb));
        }
        Fr[ks*8 + q*2]     = make_float4(fv[0], fv[1], fv[2], fv[3]);
        Fr[ks*8 + q*2 + 1] = make_float4(fv[4], fv[5], fv[6], fv[7]);
    }
    floatx4 acc[4];
    #pragma unroll
    for (int jt = 0; jt < 4; ++jt) acc[jt] = (floatx4){0.f,0.f,0.f,0.f};
    #pragma unroll
    for (int ks = 0; ks < 2; ++ks) {
        int unit = 42 + ks;
        #pragma unroll
        for (int jt = 0; jt < 4; ++jt) {
            const unsigned short* qp = wpk + (((size_t)unit*4 + jt)*64 + lane)*16;
            short8 bh = *(const short8*)qp;
            short8 bl = *(const short8*)(qp + 8);
            acc[jt] = __builtin_amdgcn_mfma_f32_16x16x32_bf16(ah[ks], bh, acc[jt], 0,0,0);
            acc[jt] = __builtin_amdgcn_mfma_f32_16x16x32_bf16(ah[ks], bl, acc[jt], 0,0,0);
            acc[jt] = __builtin_amdgcn_mfma_f32_16x16x32_bf16(al[ks], bh, acc[jt], 0,0,0);
        }
    }
    #pragma unroll
    for (int jt = 0; jt < 4; ++jt) {
        float bb = b2[jt*16 + m];
        #pragma unroll
        for (int t = 0; t < 4; ++t) {
            int row = n0 + q*4 + t;
            if (row < N) acc2[(size_t)row*64 + jt*16 + m] = acc[jt][t] + bb;
        }
    }
}

// ---------- FUSED: segemm + relu + root2 + layer-2 U planes (G==8 path) ----------
__global__ __launch_bounds__(256) void k_seghrowV(
    const unsigned short* __restrict__ Sep, const unsigned short* __restrict__ wpk,
    const float* __restrict__ acc1, float* __restrict__ acc2,
    const float* __restrict__ b2, unsigned short* __restrict__ Vbf,
    size_t plane, int N)
{
    __shared__ __align__(16) float sS[4][16][68];     // +4 pad: 2-way banks
    int lane = threadIdx.x & 63;
    int wave = threadIdx.x >> 6;
    int n0 = blockIdx.x*64 + 16*wave;
    int m = lane & 15, q = lane >> 4;
    int node = n0 + m;
    if (node >= N) node = N - 1;
    // segemm: Se @ W1B
    {
        floatx4 sacc[4];
        #pragma unroll
        for (int jt = 0; jt < 4; ++jt) sacc[jt] = (floatx4){0.f,0.f,0.f,0.f};
        for (int rel = 0; rel < 8; ++rel) {
            short8 sa = *(const short8*)(Sep + (size_t)node*256 + rel*32 + q*8);
            int unit = 32 + rel;
            #pragma unroll
            for (int jt = 0; jt < 4; ++jt) {
                const unsigned short* qp = wpk + (((size_t)unit*4 + jt)*64 + lane)*16;
                short8 bh = *(const short8*)qp;
                short8 bl = *(const short8*)(qp + 8);
                sacc[jt] = __builtin_amdgcn_mfma_f32_16x16x32_bf16(sa, bh, sacc[jt], 0,0,0);
                sacc[jt] = __builtin_amdgcn_mfma_f32_16x16x32_bf16(sa, bl, sacc[jt], 0,0,0);
            }
        }
        #pragma unroll
        for (int jt = 0; jt < 4; ++jt) {
            #pragma unroll
            for (int t = 0; t < 4; ++t)
                sS[wave][q*4 + t][jt*16 + m] = sacc[jt][t];
        }
    }
    __syncthreads();
    // h = relu(acc1 + seg) -> A-fragments (h never written to HBM)
    const float4* Fr = (const float4*)(acc1 + (size_t)node*64);
    short8 ah[2], al[2];
    #pragma unroll
    for (int ks = 0; ks < 2; ++ks) {
        float4 u0 = Fr[ks*8 + q*2];
        float4 u1 = Fr[ks*8 + q*2 + 1];
        float fv[8] = {u0.x,u0.y,u0.z,u0.w,u1.x,u1.y,u1.z,u1.w};
        #pragma unroll
        for (int i = 0; i < 8; ++i) {
            float hv = fmaxf(fv[i] + sS[wave][m][ks*32 + q*8 + i], 0.f);
            unsigned short hb = rnbf(hv);
            ah[ks][i] = (short)hb;
            al[ks][i] = (short)rnbf(hv - bf2f(hb));
        }
    }
    // root2 -> acc2
    {
        floatx4 acc[4];
        #pragma unroll
        for (int jt = 0; jt < 4; ++jt) acc[jt] = (floatx4){0.f,0.f,0.f,0.f};
        #pragma unroll
        for (int ks = 0; ks < 2; ++ks) {
            int unit = 42 + ks;
            #pragma unroll
            for (int jt = 0; jt < 4; ++jt) {
                const unsigned short* qp = wpk + (((size_t)unit*4 + jt)*64 + lane)*16;
                short8 bh = *(const short8*)qp;
                short8 bl = *(const short8*)(qp + 8);
                acc[jt] = __builtin_amdgcn_mfma_f32_16x16x32_bf16(ah[ks], bh, acc[jt], 0,0,0);
                acc[jt] = __builtin_amdgcn_mfma_f32_16x16x32_bf16(ah[ks], bl, acc[jt], 0,0,0);
                acc[jt] = __builtin_amdgcn_mfma_f32_16x16x32_bf16(al[ks], bh, acc[jt], 0,0,0);
            }
        }
        #pragma unroll
        for (int jt = 0; jt < 4; ++jt) {
            float bb = b2[jt*16 + m];
            #pragma unroll
            for (int t = 0; t < 4; ++t) {
                int row = n0 + q*4 + t;
                if (row < N) acc2[(size_t)row*64 + jt*16 + m] = acc[jt][t] + bb;
            }
        }
    }
    // 8 U planes (unitBase=16)
    for (int p = 0; p < 8; ++p) {
        floatx4 acc[4];
        #pragma unroll
        for (int jt = 0; jt < 4; ++jt) acc[jt] = (floatx4){0.f,0.f,0.f,0.f};
        #pragma unroll
        for (int ks = 0; ks < 2; ++ks) {
            int unit = 16 + p*2 + ks;
            #pragma unroll
            for (int jt = 0; jt < 4; ++jt) {
                const unsigned short* qp = wpk + (((size_t)unit*4 + jt)*64 + lane)*16;
                short8 bh = *(const short8*)qp;
                short8 bl = *(const short8*)(qp + 8);
                acc[jt] = __builtin_amdgcn_mfma_f32_16x16x32_bf16(ah[ks], bh, acc[jt], 0,0,0);
                acc[jt] = __builtin_amdgcn_mfma_f32_16x16x32_bf16(ah[ks], bl, acc[jt], 0,0,0);
                acc[jt] = __builtin_amdgcn_mfma_f32_16x16x32_bf16(al[ks], bh, acc[jt], 0,0,0);
            }
        }
        unsigned short* Vp = Vbf + (size_t)p*plane;
        #pragma unroll
        for (int jt = 0; jt < 4; ++jt) {
            #pragma unroll
            for (int t = 0; t < 4; ++t) {
                int row = n0 + q*4 + t;
                if (row < N) Vp[(size_t)row*64 + jt*16 + m] = rnbf(acc[jt][t]);
            }
        }
    }
}

// ---------- layer-2 (G==8 fast path): FLAT walk, 16-deep ----------
__global__ __launch_bounds__(256) void k_agg2f(
    const int2* __restrict__ srec, const int* __restrict__ off8,
    const unsigned short* __restrict__ Ubf, size_t plane,
    float* __restrict__ acc2, int N)
{
    int lane = threadIdx.x & 63;
    int wv = threadIdx.x >> 6;
    unsigned pl = (unsigned)plane;
    int stride = gridDim.x*4;
    for (int node = blockIdx.x*4 + wv; node < N; node += stride) {
        int o0 = rfl(off8[node*8]);
        int o8 = rfl(off8[node*8 + 8]);
        if (o0 == o8) continue;
        float add = 0.f, mx = 0.f;
        int cur = -1;
        int i = o0;
        for (; i + 16 <= o8; i += 16) {
            int2 q[16];
            #pragma unroll
            for (int u = 0; u < 16; ++u) q[u] = srec[i+u];
            int xs[16];
            #pragma unroll
            for (int u = 0; u < 16; ++u) xs[u] = rfl(q[u].x);
            float v[16];
            #pragma unroll
            for (int u = 0; u < 16; ++u) v[u] = bf2f(Ubf[vidx(xs[u], pl, lane)]);
            #pragma unroll
            for (int u = 0; u < 16; ++u)
                mstep((int)(((unsigned)xs[u] >> 24) & 7u), v[u], cur, mx, add);
        }
        for (; i + 8 <= o8; i += 8) {
            int2 q0 = srec[i+0], q1 = srec[i+1], q2 = srec[i+2], q3 = srec[i+3];
            int2 q4 = srec[i+4], q5 = srec[i+5], q6 = srec[i+6], q7 = srec[i+7];
            int x0 = rfl(q0.x), x1 = rfl(q1.x), x2 = rfl(q2.x), x3 = rfl(q3.x);
            int x4 = rfl(q4.x), x5 = rfl(q5.x), x6 = rfl(q6.x), x7 = rfl(q7.x);
            float v0 = bf2f(Ubf[vidx(x0, pl, lane)]);
            float v1 = bf2f(Ubf[vidx(x1, pl, lane)]);
            float v2 = bf2f(Ubf[vidx(x2, pl, lane)]);
            float v3 = bf2f(Ubf[vidx(x3, pl, lane)]);
            float v4 = bf2f(Ubf[vidx(x4, pl, lane)]);
            float v5 = bf2f(Ubf[vidx(x5, pl, lane)]);
            float v6 = bf2f(Ubf[vidx(x6, pl, lane)]);
            float v7 = bf2f(Ubf[vidx(x7, pl, lane)]);
            mstep((int)(((unsigned)x0 >> 24) & 7u), v0, cur, mx, add);
            mstep((int)(((unsigned)x1 >> 24) & 7u), v1, cur, mx, add);
            mstep((int)(((unsigned)x2 >> 24) & 7u), v2, cur, mx, add);
            mstep((int)(((unsigned)x3 >> 24) & 7u), v3, cur, mx, add);
            mstep((int)(((unsigned)x4 >> 24) & 7u), v4, cur, mx, add);
            mstep((int)(((unsigned)x5 >> 24) & 7u), v5, cur, mx, add);
            mstep((int)(((unsigned)x6 >> 24) & 7u), v6, cur, mx, add);
            mstep((int)(((unsigned)x7 >> 24) & 7u), v7, cur, mx, add);
        }
        for (; i < o8; ++i) {
            int xx = rfl(srec[i].x);
            float v = bf2f(Ubf[vidx(xx, pl, lane)]);
            mstep((int)(((unsigned)xx >> 24) & 7u), v, cur, mx, add);
        }
        add += mx;
        acc2[(size_t)node*64 + lane] += add;
    }
}

// ---------- layer-2 (fallback G<8) ----------
__global__ __launch_bounds__(256) void k_agg2(
    const int2* __restrict__ srec, const int* __restrict__ off8,
    const unsigned short* __restrict__ Ubf, size_t plane,
    float* __restrict__ acc2, int N, int g0, int g1)
{
    int lane = threadIdx.x & 63;
    int wv = threadIdx.x >> 6;
    int stride = gridDim.x*4;
    const float NEG = -__builtin_inff();
    for (int node = blockIdx.x*4 + wv; node < N; node += stride) {
        float add = 0.f;
        bool any = false;
        for (int r = g0; r < g1; ++r) {
            int s = rfl(off8[node*8 + r]);
            int e = rfl(off8[node*8 + r + 1]);
            if (s == e) continue;
            any = true;
            const unsigned short* Up = Ubf + (size_t)(r - g0)*plane;
            float mx = NEG;
            int i = s;
            for (; i + 8 <= e; i += 8) {
                int s0 = rfl(srec[i+0].x) & 0xFFFFFF, s1 = rfl(srec[i+1].x) & 0xFFFFFF;
                int s2 = rfl(srec[i+2].x) & 0xFFFFFF, s3 = rfl(srec[i+3].x) & 0xFFFFFF;
                int s4 = rfl(srec[i+4].x) & 0xFFFFFF, s5 = rfl(srec[i+5].x) & 0xFFFFFF;
                int s6 = rfl(srec[i+6].x) & 0xFFFFFF, s7 = rfl(srec[i+7].x) & 0xFFFFFF;
                float v0 = bf2f(Up[(size_t)s0*64 + lane]), v1 = bf2f(Up[(size_t)s1*64 + lane]);
                float v2 = bf2f(Up[(size_t)s2*64 + lane]), v3 = bf2f(Up[(size_t)s3*64 + lane]);
                float v4 = bf2f(Up[(size_t)s4*64 + lane]), v5 = bf2f(Up[(size_t)s5*64 + lane]);
                float v6 = bf2f(Up[(size_t)s6*64 + lane]), v7 = bf2f(Up[(size_t)s7*64 + lane]);
                float m01 = fmaxf(v0, v1), m23 = fmaxf(v2, v3);
                float m45 = fmaxf(v4, v5), m67 = fmaxf(v6, v7);
                mx = fmaxf(mx, fmaxf(fmaxf(m01, m23), fmaxf(m45, m67)));
            }
            for (; i < e; ++i) {
                int sx = rfl(srec[i].x) & 0xFFFFFF;
                mx = fmaxf(mx, bf2f(Up[(size_t)sx*64 + lane]));
            }
            add += mx;
        }
        if (any) acc2[(size_t)node*64 + lane] += add;
    }
}

// ---------- head via MFMA ----------
__global__ __launch_bounds__(256) void k_finB(
    const float* __restrict__ acc2, const float* __restrict__ omega,
    const float* __restrict__ Wo, const float* __restrict__ bo,
    const unsigned short* __restrict__ wpk,
    const float* __restrict__ bagg, const float* __restrict__ Wc,
    const float* __restrict__ bc, float* __restrict__ out, int N)
{
    int lane = threadIdx.x & 63;
    int wave = threadIdx.x >> 6;
    int n0 = blockIdx.x*64 + 16*wave;
    int m = lane & 15, q = lane >> 4;
    int node = n0 + m;
    if (node >= N) node = N - 1;
    short8 ah[4], al[4];
    const float4* Fr = (const float4*)(acc2 + (size_t)node*64);
    #pragma unroll
    for (int ks = 0; ks < 2; ++ks) {
        float4 u0 = Fr[ks*8 + q*2];
        float4 u1 = Fr[ks*8 + q*2 + 1];
        float fv[8] = {u0.x,u0.y,u0.z,u0.w,u1.x,u1.y,u1.z,u1.w};
        #pragma unroll
        for (int i = 0; i < 8; ++i) {
            float hv = fmaxf(fv[i], 0.f);
            unsigned short hb = rnbf(hv);
            ah[ks][i] = (short)hb;
            al[ks][i] = (short)rnbf(hv - bf2f(hb));
        }
    }
    float om0 = omega[2*node], om1 = omega[2*node+1];
    #pragma unroll
    for (int ks = 2; ks < 4; ++ks) {
        #pragma unroll
        for (int i = 0; i < 8; ++i) {
            int f = (ks - 2)*32 + q*8 + i;
            float ov = fmaxf(fmaf(om1, Wo[64+f], fmaf(om0, Wo[f], bo[f])), 0.f);
            unsigned short hb = rnbf(ov);
            ah[ks][i] = (short)hb;
            al[ks][i] = (short)rnbf(ov - bf2f(hb));
        }
    }
    floatx4 acc[4];
    #pragma unroll
    for (int jt = 0; jt < 4; ++jt) acc[jt] = (floatx4){0.f,0.f,0.f,0.f};
    #pragma unroll
    for (int ks = 0; ks < 4; ++ks) {
        int unit = 44 + ks;
        #pragma unroll
        for (int jt = 0; jt < 4; ++jt) {
            const unsigned short* qp = wpk + (((size_t)unit*4 + jt)*64 + lane)*16;
            short8 bh = *(const short8*)qp;
            short8 bl = *(const short8*)(qp + 8);
            acc[jt] = __builtin_amdgcn_mfma_f32_16x16x32_bf16(ah[ks], bh, acc[jt], 0,0,0);
            acc[jt] = __builtin_amdgcn_mfma_f32_16x16x32_bf16(ah[ks], bl, acc[jt], 0,0,0);
            acc[jt] = __builtin_amdgcn_mfma_f32_16x16x32_bf16(al[ks], bh, acc[jt], 0,0,0);
        }
    }
    float bg0 = bagg[m], bg1 = bagg[16+m], bg2 = bagg[32+m], bg3 = bagg[48+m];
    float wc0 = Wc[m],   wc1 = Wc[16+m],   wc2 = Wc[32+m],   wc3 = Wc[48+m];
    float bc0 = bc[0];
    #pragma unroll
    for (int t = 0; t < 4; ++t) {
        float s = fmaxf(acc[0][t] + bg0, 0.f)*wc0
                + fmaxf(acc[1][t] + bg1, 0.f)*wc1
                + fmaxf(acc[2][t] + bg2, 0.f)*wc2
                + fmaxf(acc[3][t] + bg3, 0.f)*wc3;
        s += __shfl_xor(s, 1);
        s += __shfl_xor(s, 2);
        s += __shfl_xor(s, 4);
        s += __shfl_xor(s, 8);
        int row = n0 + q*4 + t;
        if (m == 0 && row < N) out[row] = tanhf(s + bc0) * 5.0f;
    }
}

extern "C" void kernel_launch(void* const* d_in, const int* in_sizes, int n_in,
                              void* d_out, int out_size, void* d_ws, size_t ws_size,
                              hipStream_t stream)
{
    const float* x      = (const float*)d_in[0];
    const int*   ei     = (const int*)d_in[1];
    const float* ea     = (const float*)d_in[2];
    const int*   et     = (const int*)d_in[3];
    const float* omega  = (const float*)d_in[4];
    const float* Wn     = (const float*)d_in[5];
    const float* bn     = (const float*)d_in[6];
    const float* We     = (const float*)d_in[7];
    const float* be     = (const float*)d_in[8];
    const float* Wo     = (const float*)d_in[9];
    const float* bo     = (const float*)d_in[10];
    const float* W1     = (const float*)d_in[11];
    const float* Wroot1 = (const float*)d_in[12];
    const float* b1     = (const float*)d_in[13];
    const float* W2     = (const float*)d_in[14];
    const float* Wroot2 = (const float*)d_in[15];
    const float* b2     = (const float*)d_in[16];
    const float* Wagg   = (const float*)d_in[17];
    const float* bagg   = (const float*)d_in[18];
    const float* Wc     = (const float*)d_in[19];
    const float* bc     = (const float*)d_in[20];
    int N = in_sizes[0] / 3;
    int E = in_sizes[3];
    float* out = (float*)d_out;

    int K8 = N*8;
    int nb = (K8 + SCHUNK - 1)/SCHUNK;

    // ---- workspace layout: every carve 256B-aligned ----
    #define ALIGN256(p) ((char*)(((size_t)(p) + 255) & ~(size_t)255))
    char* pp = (char*)d_ws;
    float* nbuf   = (float*)pp;  pp = ALIGN256(pp + (size_t)N*64*4);     // fallback n; reused as acc2
    float* acc1   = (float*)pp;  pp = ALIGN256(pp + (size_t)N*64*4);
    int2*  srec   = (int2*)pp;   pp = ALIGN256(pp + (size_t)E*8);
    int*   deg8   = (int*)pp;    pp = ALIGN256(pp + (size_t)K8*4);       // bktCnt(512) + cursorRel(512) on fast path
    int*   off8   = (int*)pp;    pp = ALIGN256(pp + (size_t)(K8+1)*4);
    int*   cursor = (int*)pp;    pp = ALIGN256(pp + (size_t)K8*4);
    int*   bsum   = (int*)pp;    pp = ALIGN256(pp + (size_t)nb*4);
    unsigned short* wpk = (unsigned short*)pp;
    pp = ALIGN256(pp + (size_t)48*4*64*16*2);                            // 384 KB
    unsigned short* Sepool = (unsigned short*)pp;
    pp = ALIGN256(pp + (size_t)N*256*2);                                 // 51 MB
    size_t off = (size_t)(pp - (char*)d_ws);
    size_t planeElems = (size_t)N*64;
    size_t avail = (ws_size > off) ? (ws_size - off) : 0;
    int G = (int)(avail / (planeElems*2));
    if (G > 8) G = 8;
    if (G < 1) G = 1;
    unsigned short* Vbf = (unsigned short*)pp;
    float* acc2 = nbuf;

    int gblocks = (N + 63)/64;
    int nbkt = (N + 511) >> 9;
    bool fastSort = (N <= 131072) && ((size_t)E*8 <= (size_t)N*256*2);
    int* bktCnt = deg8;
    int* cursorRel = deg8 + 512;

    // ---- memset first (bucket counters), then weight pack ----
    if (fastSort) hipMemsetAsync(deg8, 0, 4096, stream);
    else          hipMemsetAsync(deg8, 0, (size_t)K8*4, stream);
    k_wpack<<<192, 64, 0, stream>>>(W1, W2, Wroot1, Wroot2, Wagg, wpk);

    // ---- phase 1: encoder/planes || bucket count (role-split) ----
    if (G == 8 && fastSort) {
        k_phase1<<<gblocks + CNTB, 256, 0, stream>>>(x, Wn, bn, wpk, b1, acc1, Vbf,
                                                     planeElems, N, ei, bktCnt, E, nbkt,
                                                     gblocks, CNTB);
    } else if (G == 8) {
        k_phase1<<<gblocks, 256, 0, stream>>>(x, Wn, bn, wpk, b1, acc1, Vbf,
                                              planeElems, N, ei, bktCnt, E, nbkt,
                                              gblocks, 0);
    } else {
        k_encB<<<gblocks, 256, 0, stream>>>(x, Wn, bn, wpk, b1, nbuf, acc1, N);
        if (fastSort)
            k_phase1<<<CNTB, 256, 0, stream>>>(x, Wn, bn, wpk, b1, acc1, Vbf,
                                               planeElems, N, ei, bktCnt, E, nbkt,
                                               0, CNTB);
    }

    // ---- edge sort ----
    if (fastSort) {
        int2* tmp = (int2*)Sepool;                    // Sepool free until k_agg1ef
        k_partA<<<(E + PA_CH - 1)/PA_CH, 256, 0, stream>>>(ei, ea, et, bktCnt,
                                                           cursorRel, tmp, E, nbkt);
        k_partB2<<<nbkt, 256, 0, stream>>>(tmp, bktCnt, off8, srec, K8, nbkt);
    } else {
        k_histd<<<(E + 255)/256, 256, 0, stream>>>(ei, et, deg8, E);
        k_bsum<<<nb, 256, 0, stream>>>(deg8, bsum, K8);
        k_bscan<<<1, 256, 0, stream>>>(bsum, nb);
        k_bapply<<<nb, 256, 0, stream>>>(deg8, bsum, off8, cursor, K8);
        k_scatd<<<(E + 255)/256, 256, 0, stream>>>(ei, ea, et, cursor, srec, E);
    }

    int aggBlocks = 4096;
    if (G == 8) {
        k_agg1ef<<<aggBlocks, 256, 0, stream>>>(srec, off8, Vbf, planeElems, We, be,
                                                acc1, Sepool, N);
        k_seghrowV<<<gblocks, 256, 0, stream>>>(Sepool, wpk, acc1, acc2, b2,
                                                Vbf, planeElems, N);
        k_agg2f<<<aggBlocks, 256, 0, stream>>>(srec, off8, Vbf, planeElems, acc2, N);
    } else {
        int Gc1 = G;
        k_vgemmB<<<gblocks, 256, 0, stream>>>(nbuf, wpk, 0, 0, Gc1, Vbf, planeElems, N);
        k_agg1e<<<aggBlocks, 256, 0, stream>>>(srec, off8, Vbf, planeElems, We, be,
                                               acc1, Sepool, N, Gc1);
        for (int g0 = Gc1; g0 < 8; g0 += G) {
            int Gc = (8 - g0 < G) ? (8 - g0) : G;
            k_vgemmB<<<gblocks, 256, 0, stream>>>(nbuf, wpk, 0, g0, Gc, Vbf, planeElems, N);
            k_agg1v<<<aggBlocks, 256, 0, stream>>>(srec, off8, Vbf, planeElems,
                                                   acc1, N, g0, g0 + Gc);
        }
        k_segemm<<<gblocks, 256, 0, stream>>>(Sepool, wpk, acc1, N);
        k_hrowB<<<gblocks, 256, 0, stream>>>(acc1, acc2, wpk, b2, N);
        for (int g0 = 0; g0 < 8; g0 += G) {
            int Gc = (8 - g0 < G) ? (8 - g0) : G;
            k_vgemmB<<<gblocks, 256, 0, stream>>>(acc1, wpk, 16, g0, Gc, Vbf, planeElems, N);
            k_agg2<<<aggBlocks, 256, 0, stream>>>(srec, off8, Vbf, planeElems,
                                                  acc2, N, g0, g0 + Gc);
        }
    }
    k_finB<<<gblocks, 256, 0, stream>>>(acc2, omega, Wo, bo, wpk, bagg, Wc, bc, out, N);
}